// Round 1
// baseline (747.919 us; speedup 1.0000x reference)
//
#include <hip/hip_runtime.h>

typedef unsigned short u16;
typedef float f32x4 __attribute__((ext_vector_type(4)));
typedef __bf16 bf16x8 __attribute__((ext_vector_type(8)));

#define S_LEN 2048
#define DM 2048
#define NHEAD 32
#define DHEAD 64

__device__ __forceinline__ u16 f2bf(float f) {
    __bf16 b = (__bf16)f;
    return __builtin_bit_cast(u16, b);
}
__device__ __forceinline__ float bf2f(u16 u) {
    return (float)__builtin_bit_cast(__bf16, u);
}
// async global->LDS, 16B per lane. LDS dest must be base + lane*16 within each wave.
__device__ __forceinline__ void async16(const void* g, void* l) {
    __builtin_amdgcn_global_load_lds(
        (const __attribute__((address_space(1))) unsigned int*)g,
        (__attribute__((address_space(3))) unsigned int*)l, 16, 0, 0);
}

// ---------------- cast f32 -> bf16 (4 elems/thread) ----------------
__global__ __launch_bounds__(256) void cast_kernel(const float* __restrict__ in,
                                                   u16* __restrict__ out, long long n) {
    long long i = ((long long)blockIdx.x * 256 + threadIdx.x) * 4;
    if (i + 3 < n) {
        float4 f = *(const float4*)(in + i);
        u16 o0 = f2bf(f.x), o1 = f2bf(f.y), o2 = f2bf(f.z), o3 = f2bf(f.w);
        u16* p = out + i;
        ushort4 v; v.x = o0; v.y = o1; v.z = o2; v.w = o3;
        *(ushort4*)p = v;
    }
}

// ---------------- RoPE in-place on [4096][2048] bf16, scale folded ----------------
__global__ __launch_bounds__(256) void rope_kernel(u16* __restrict__ T, float scale) {
    int idx = blockIdx.x * 256 + threadIdx.x;   // 4096 rows * 32 heads * 32 j
    int j = idx & 31;
    int h = (idx >> 5) & 31;
    long long row = idx >> 10;                  // 0..4095 (b*2048 + s)
    int s = (int)(row & (S_LEN - 1));
    long long base = row * DM + h * DHEAD;
    // inv_freq = 10000^(-j/32) = exp(-j * ln(10000)/32)
    float inv = __expf(-(float)j * (9.210340371976184f / 32.0f));
    float th = (float)s * inv;
    float c = cosf(th), sn = sinf(th);
    float x1 = bf2f(T[base + j]);
    float x2 = bf2f(T[base + 32 + j]);
    float y1 = (x1 * c - x2 * sn) * scale;
    float y2 = (x2 * c + x1 * sn) * scale;
    T[base + j] = f2bf(y1);
    T[base + 32 + j] = f2bf(y2);
}

// ---------------- GEMM: C[M][N] = A[M][K] * Bt[N][K]^T + bias ----------------
// 128x128 tile, BK=32, 4 waves (2x2), each wave 4x4 16x16x32 MFMAs.
template <int BF16OUT>
__global__ __launch_bounds__(256) void gemm_bt(const u16* __restrict__ A,
                                               const u16* __restrict__ Bt,
                                               const float* __restrict__ bias,
                                               void* __restrict__ Cout,
                                               int M, int N, int K) {
    __shared__ __align__(16) u16 As[128 * 32];
    __shared__ __align__(16) u16 Bs[128 * 32];
    int tid = threadIdx.x;
    int w = tid >> 6, lane = tid & 63, quad = lane >> 4, l16 = lane & 15;
    int m0 = blockIdx.x * 128;
    int n0 = blockIdx.y * 128;
    int wm = (w & 1) * 64, wn = (w >> 1) * 64;

    f32x4 acc[4][4] = {};

    const u16* ga = A + (long long)m0 * K;
    const u16* gb = Bt + (long long)n0 * K;

    for (int k0 = 0; k0 < K; k0 += 32) {
#pragma unroll
        for (int rr = 0; rr < 2; ++rr) {
            int c = tid + rr * 256;          // 0..511
            int row = c >> 2, kc = c & 3;    // LDS row-major [128][32]
            async16(ga + (long long)row * K + k0 + kc * 8, (char*)As + c * 16);
            async16(gb + (long long)row * K + k0 + kc * 8, (char*)Bs + c * 16);
        }
        __syncthreads();
        bf16x8 af[4], bfv[4];
#pragma unroll
        for (int mt = 0; mt < 4; ++mt)
            af[mt] = *(const bf16x8*)(As + (wm + mt * 16 + l16) * 32 + quad * 8);
#pragma unroll
        for (int nt = 0; nt < 4; ++nt)
            bfv[nt] = *(const bf16x8*)(Bs + (wn + nt * 16 + l16) * 32 + quad * 8);
#pragma unroll
        for (int mt = 0; mt < 4; ++mt)
#pragma unroll
            for (int nt = 0; nt < 4; ++nt)
                acc[mt][nt] = __builtin_amdgcn_mfma_f32_16x16x32_bf16(af[mt], bfv[nt],
                                                                      acc[mt][nt], 0, 0, 0);
        __syncthreads();
    }

#pragma unroll
    for (int mt = 0; mt < 4; ++mt) {
#pragma unroll
        for (int nt = 0; nt < 4; ++nt) {
            int col = n0 + wn + nt * 16 + l16;
            float bv = bias[col];
#pragma unroll
            for (int r = 0; r < 4; ++r) {
                int row = m0 + wm + mt * 16 + quad * 4 + r;
                float v = acc[mt][nt][r] + bv;
                if (BF16OUT)
                    ((u16*)Cout)[(long long)row * N + col] = f2bf(v);
                else
                    ((float*)Cout)[(long long)row * N + col] = v;
            }
        }
    }
}

// ---------------- Flash attention, causal, sigmoid(V) ----------------
// grid = B * NHEAD * (S/64); block = 256 (4 waves, 16 q-rows each)
__global__ __launch_bounds__(256) void flash_attn(const u16* __restrict__ Q,
                                                  const u16* __restrict__ K,
                                                  const u16* __restrict__ V,
                                                  u16* __restrict__ Y) {
    int bid = blockIdx.x;
    int qt = bid & 31;
    int h = (bid >> 5) & 31;
    int b = bid >> 10;
    int tid = threadIdx.x;
    int w = tid >> 6, lane = tid & 63, quad = lane >> 4, l16 = lane & 15;

    __shared__ __align__(16) u16 Kl[64 * 64];        // [kc][d]
    __shared__ __align__(16) u16 Vt[64 * 64];        // [d][kc], sigmoid applied
    __shared__ __align__(16) u16 Pl[4][16 * 72];     // per-wave [q][kc], stride 72

    // Q fragments (RoPE+scale already applied; A-layout direct from global)
    int qrow = qt * 64 + w * 16 + l16;
    const u16* qp = Q + ((long long)(b * S_LEN + qrow)) * DM + h * DHEAD + quad * 8;
    bf16x8 aq0 = *(const bf16x8*)(qp);
    bf16x8 aq1 = *(const bf16x8*)(qp + 32);

    f32x4 o[4] = {};
    float m_r[4], l_r[4];
#pragma unroll
    for (int r = 0; r < 4; ++r) { m_r[r] = -__builtin_inff(); l_r[r] = 0.f; }

    int ktiles = qt + 1;
    for (int kt = 0; kt < ktiles; ++kt) {
        int k0 = kt * 64;
        // ---- stage K tile via async copy (layout matches linear lane order) ----
        const u16* gk = K + ((long long)(b * S_LEN + k0)) * DM + h * DHEAD;
#pragma unroll
        for (int rr = 0; rr < 2; ++rr) {
            int c = tid + rr * 256;            // 512 chunks of 16B
            int kc = c >> 3, dc = c & 7;
            async16(gk + (long long)kc * DM + dc * 8, (char*)Kl + c * 16);
        }
        // ---- stage sigmoid(V) transposed ----
        {
            const u16* gv = V + ((long long)(b * S_LEN + k0)) * DM + h * DHEAD;
            int kc = tid >> 2, d0 = (tid & 3) * 16;
#pragma unroll
            for (int half = 0; half < 2; ++half) {
                bf16x8 vv = *(const bf16x8*)(gv + (long long)kc * DM + d0 + half * 8);
#pragma unroll
                for (int j = 0; j < 8; ++j) {
                    float vf = (float)vv[j];
                    float sg = 1.f / (1.f + __expf(-vf));
                    Vt[(d0 + half * 8 + j) * 64 + kc] = f2bf(sg);
                }
            }
        }
        __syncthreads();

        // ---- S = Q K^T (scale pre-folded into Q) ----
        f32x4 s[4];
#pragma unroll
        for (int nt = 0; nt < 4; ++nt) {
            f32x4 a = {};
            bf16x8 bk0 = *(const bf16x8*)(Kl + (nt * 16 + l16) * 64 + quad * 8);
            bf16x8 bk1 = *(const bf16x8*)(Kl + (nt * 16 + l16) * 64 + 32 + quad * 8);
            a = __builtin_amdgcn_mfma_f32_16x16x32_bf16(aq0, bk0, a, 0, 0, 0);
            a = __builtin_amdgcn_mfma_f32_16x16x32_bf16(aq1, bk1, a, 0, 0, 0);
            s[nt] = a;
        }
        // causal mask (diagonal tile only)
        if (kt == qt) {
#pragma unroll
            for (int nt = 0; nt < 4; ++nt) {
                int kcg = k0 + nt * 16 + l16;
#pragma unroll
                for (int r = 0; r < 4; ++r) {
                    int qg = qt * 64 + w * 16 + quad * 4 + r;
                    if (kcg > qg) s[nt][r] = -__builtin_inff();
                }
            }
        }
        // ---- online softmax (rows live across the 16 lanes of each quad) ----
        float mnew[4], alpha[4];
#pragma unroll
        for (int r = 0; r < 4; ++r) {
            float mx = fmaxf(fmaxf(s[0][r], s[1][r]), fmaxf(s[2][r], s[3][r]));
#pragma unroll
            for (int off = 1; off < 16; off <<= 1)
                mx = fmaxf(mx, __shfl_xor(mx, off, 64));
            mnew[r] = fmaxf(m_r[r], mx);
            alpha[r] = __expf(m_r[r] - mnew[r]);
            m_r[r] = mnew[r];
        }
#pragma unroll
        for (int nt = 0; nt < 4; ++nt)
#pragma unroll
            for (int r = 0; r < 4; ++r)
                s[nt][r] = __expf(s[nt][r] - mnew[r]);
#pragma unroll
        for (int r = 0; r < 4; ++r) {
            float sum = s[0][r] + s[1][r] + s[2][r] + s[3][r];
#pragma unroll
            for (int off = 1; off < 16; off <<= 1)
                sum += __shfl_xor(sum, off, 64);
            l_r[r] = l_r[r] * alpha[r] + sum;
#pragma unroll
            for (int dt = 0; dt < 4; ++dt) o[dt][r] *= alpha[r];
        }
        // ---- P: C-layout -> LDS -> A-layout ----
        u16* pw = &Pl[w][0];
#pragma unroll
        for (int nt = 0; nt < 4; ++nt)
#pragma unroll
            for (int r = 0; r < 4; ++r)
                pw[(quad * 4 + r) * 72 + nt * 16 + l16] = f2bf(s[nt][r]);
        __syncthreads();

        bf16x8 ap0 = *(const bf16x8*)(pw + l16 * 72 + quad * 8);
        bf16x8 ap1 = *(const bf16x8*)(pw + l16 * 72 + 32 + quad * 8);
#pragma unroll
        for (int dt = 0; dt < 4; ++dt) {
            bf16x8 bv0 = *(const bf16x8*)(Vt + (dt * 16 + l16) * 64 + quad * 8);
            bf16x8 bv1 = *(const bf16x8*)(Vt + (dt * 16 + l16) * 64 + 32 + quad * 8);
            o[dt] = __builtin_amdgcn_mfma_f32_16x16x32_bf16(ap0, bv0, o[dt], 0, 0, 0);
            o[dt] = __builtin_amdgcn_mfma_f32_16x16x32_bf16(ap1, bv1, o[dt], 0, 0, 0);
        }
        __syncthreads();
    }

    // ---- epilogue: divide by l, store bf16 ----
#pragma unroll
    for (int dt = 0; dt < 4; ++dt) {
#pragma unroll
        for (int r = 0; r < 4; ++r) {
            float val = o[dt][r] / l_r[r];
            int qg = qt * 64 + w * 16 + quad * 4 + r;
            Y[((long long)(b * S_LEN + qg)) * DM + h * DHEAD + dt * 16 + l16] = f2bf(val);
        }
    }
}

extern "C" void kernel_launch(void* const* d_in, const int* in_sizes, int n_in,
                              void* d_out, int out_size, void* d_ws, size_t ws_size,
                              hipStream_t stream) {
    const float* x  = (const float*)d_in[0];
    const float* Wq = (const float*)d_in[1];
    const float* bq = (const float*)d_in[2];
    const float* Wk = (const float*)d_in[3];
    const float* bk = (const float*)d_in[4];
    const float* Wv = (const float*)d_in[5];
    const float* bv = (const float*)d_in[6];
    const float* Wo = (const float*)d_in[7];
    const float* bo = (const float*)d_in[8];

    const long long M = 2LL * S_LEN;       // 4096
    const long long NX = M * DM;           // 8388608
    const long long NW = (long long)DM * DM;  // 4194304

    char* ws = (char*)d_ws;
    u16* xb  = (u16*)(ws);                        // 16 MB
    u16* Wqb = (u16*)(ws + 16 * 1024 * 1024);     // 8 MB each
    u16* Wkb = (u16*)(ws + 24 * 1024 * 1024);
    u16* Wvb = (u16*)(ws + 32 * 1024 * 1024);
    u16* Wob = (u16*)(ws + 40 * 1024 * 1024);
    u16* Qb  = (u16*)(ws + 48 * 1024 * 1024);     // 16 MB each
    u16* Kb  = (u16*)(ws + 64 * 1024 * 1024);
    u16* Vb  = (u16*)(ws + 80 * 1024 * 1024);
    u16* Yb  = (u16*)(ws + 96 * 1024 * 1024);

    cast_kernel<<<(int)(NX / 1024), 256, 0, stream>>>(x, xb, NX);
    cast_kernel<<<(int)(NW / 1024), 256, 0, stream>>>(Wq, Wqb, NW);
    cast_kernel<<<(int)(NW / 1024), 256, 0, stream>>>(Wk, Wkb, NW);
    cast_kernel<<<(int)(NW / 1024), 256, 0, stream>>>(Wv, Wvb, NW);
    cast_kernel<<<(int)(NW / 1024), 256, 0, stream>>>(Wo, Wob, NW);

    dim3 gg(32, 16);
    gemm_bt<1><<<gg, 256, 0, stream>>>(xb, Wqb, bq, Qb, (int)M, DM, DM);
    gemm_bt<1><<<gg, 256, 0, stream>>>(xb, Wkb, bk, Kb, (int)M, DM, DM);
    gemm_bt<1><<<gg, 256, 0, stream>>>(xb, Wvb, bv, Vb, (int)M, DM, DM);

    // RoPE on Q (scale 1/sqrt(64) folded in) and K
    rope_kernel<<<16384, 256, 0, stream>>>(Qb, 0.125f);
    rope_kernel<<<16384, 256, 0, stream>>>(Kb, 1.0f);

    flash_attn<<<2 * NHEAD * (S_LEN / 64), 256, 0, stream>>>(Qb, Kb, Vb, Yb);

    gemm_bt<0><<<gg, 256, 0, stream>>>(Yb, Wob, bo, d_out, (int)M, DM, DM);
}

// Round 2
// 470.412 us; speedup vs baseline: 1.5899x; 1.5899x over previous
//
#include <hip/hip_runtime.h>

typedef unsigned short u16;
typedef float f32x4 __attribute__((ext_vector_type(4)));
typedef __bf16 bf16x8 __attribute__((ext_vector_type(8)));

#define S_LEN 2048
#define DM 2048
#define NHEAD 32
#define DHEAD 64

__device__ __forceinline__ u16 f2bf(float f) {
    __bf16 b = (__bf16)f;
    return __builtin_bit_cast(u16, b);
}
__device__ __forceinline__ float bf2f(u16 u) {
    return (float)__builtin_bit_cast(__bf16, u);
}
// async global->LDS, 16B per lane. LDS dest must be wave-uniform base + lane*16.
__device__ __forceinline__ void async16(const void* g, void* l) {
    __builtin_amdgcn_global_load_lds(
        (const __attribute__((address_space(1))) unsigned int*)g,
        (__attribute__((address_space(3))) unsigned int*)l, 16, 0, 0);
}

// ---------------- cast f32 -> bf16 (4 elems/thread) ----------------
__global__ __launch_bounds__(256) void cast_kernel(const float* __restrict__ in,
                                                   u16* __restrict__ out, long long n) {
    long long i = ((long long)blockIdx.x * 256 + threadIdx.x) * 4;
    if (i + 3 < n) {
        float4 f = *(const float4*)(in + i);
        ushort4 v;
        v.x = f2bf(f.x); v.y = f2bf(f.y); v.z = f2bf(f.z); v.w = f2bf(f.w);
        *(ushort4*)(out + i) = v;
    }
}

// ---------------- RoPE in-place on [4096][2048] bf16, scale folded ----------------
__global__ __launch_bounds__(256) void rope_kernel(u16* __restrict__ T, float scale) {
    int idx = blockIdx.x * 256 + threadIdx.x;   // 4096 rows * 32 heads * 32 j
    int j = idx & 31;
    int h = (idx >> 5) & 31;
    long long row = idx >> 10;                  // 0..4095 (b*2048 + s)
    int s = (int)(row & (S_LEN - 1));
    long long base = row * DM + h * DHEAD;
    float inv = __expf(-(float)j * (9.210340371976184f / 32.0f));
    float th = (float)s * inv;
    float c = cosf(th), sn = sinf(th);
    float x1 = bf2f(T[base + j]);
    float x2 = bf2f(T[base + 32 + j]);
    T[base + j] = f2bf((x1 * c - x2 * sn) * scale);
    T[base + 32 + j] = f2bf((x2 * c + x1 * sn) * scale);
}

// ---------------- sigmoid(V) transpose: Vb[4096][2048] -> VT[(b,h)*64+d][2048] ----------------
__global__ __launch_bounds__(256) void vsigt_kernel(const u16* __restrict__ V,
                                                    u16* __restrict__ VT) {
    int st = blockIdx.x & 63;        // 64-row s-tile over 4096 rows
    int h = blockIdx.x >> 6;         // head
    __shared__ u16 T[64][72];
    int r = threadIdx.x >> 2, c0 = (threadIdx.x & 3) * 16;
    const u16* src = V + (long long)(st * 64 + r) * DM + h * 64 + c0;
#pragma unroll
    for (int half = 0; half < 2; ++half) {
        bf16x8 v = *(const bf16x8*)(src + half * 8);
#pragma unroll
        for (int j = 0; j < 8; ++j) {
            float vf = (float)v[j];
            T[c0 + half * 8 + j][r] = f2bf(1.f / (1.f + __expf(-vf)));
        }
    }
    __syncthreads();
    int d = threadIdx.x >> 2, s0 = (threadIdx.x & 3) * 16;
    int b = st >> 5;
    int sl = (st & 31) * 64;
    u16* dst = VT + ((long long)((b * NHEAD + h) * DHEAD + d)) * S_LEN + sl + s0;
#pragma unroll
    for (int q = 0; q < 4; ++q)
        *(ushort4*)(dst + q * 4) = *(const ushort4*)(&T[d][s0] + q * 4);
}

// ---------------- merged QKV GEMM: A[4096][2048] x Wqkv[6144][2048]^T ----------------
__global__ __launch_bounds__(256) void gemm_qkv(const u16* __restrict__ A,
                                                const u16* __restrict__ Bt,
                                                const float* __restrict__ bq,
                                                const float* __restrict__ bk,
                                                const float* __restrict__ bv,
                                                u16* __restrict__ Qo, u16* __restrict__ Ko,
                                                u16* __restrict__ Vo, int M, int K) {
    __shared__ __align__(16) u16 As[128 * 32];
    __shared__ __align__(16) u16 Bs[128 * 32];
    int tid = threadIdx.x;
    int w = tid >> 6, lane = tid & 63, quad = lane >> 4, l16 = lane & 15;
    int m0 = blockIdx.x * 128;
    int n0 = blockIdx.y * 128;       // 0..6143
    int sel = n0 >> 11;
    int nloc = n0 & 2047;
    u16* out = sel == 0 ? Qo : (sel == 1 ? Ko : Vo);
    const float* bias = sel == 0 ? bq : (sel == 1 ? bk : bv);
    int wm = (w & 1) * 64, wn = (w >> 1) * 64;

    f32x4 acc[4][4] = {};
    const u16* ga = A + (long long)m0 * K;
    const u16* gb = Bt + (long long)n0 * K;

    for (int k0 = 0; k0 < K; k0 += 32) {
#pragma unroll
        for (int rr = 0; rr < 2; ++rr) {
            int c = tid + rr * 256;
            int row = c >> 2, kc = c & 3;
            async16(ga + (long long)row * K + k0 + kc * 8, (char*)As + c * 16);
            async16(gb + (long long)row * K + k0 + kc * 8, (char*)Bs + c * 16);
        }
        __syncthreads();
        bf16x8 af[4], bfv[4];
#pragma unroll
        for (int mt = 0; mt < 4; ++mt)
            af[mt] = *(const bf16x8*)(As + (wm + mt * 16 + l16) * 32 + quad * 8);
#pragma unroll
        for (int nt = 0; nt < 4; ++nt)
            bfv[nt] = *(const bf16x8*)(Bs + (wn + nt * 16 + l16) * 32 + quad * 8);
#pragma unroll
        for (int mt = 0; mt < 4; ++mt)
#pragma unroll
            for (int nt = 0; nt < 4; ++nt)
                acc[mt][nt] = __builtin_amdgcn_mfma_f32_16x16x32_bf16(af[mt], bfv[nt],
                                                                      acc[mt][nt], 0, 0, 0);
        __syncthreads();
    }

#pragma unroll
    for (int mt = 0; mt < 4; ++mt) {
#pragma unroll
        for (int nt = 0; nt < 4; ++nt) {
            int col = nloc + wn + nt * 16 + l16;
            float bvs = bias[col];
#pragma unroll
            for (int r = 0; r < 4; ++r) {
                int row = m0 + wm + mt * 16 + quad * 4 + r;
                out[(long long)row * 2048 + col] = f2bf(acc[mt][nt][r] + bvs);
            }
        }
    }
}

// ---------------- GEMM: C[M][N] = A[M][K] * Bt[N][K]^T + bias (f32 out) ----------------
__global__ __launch_bounds__(256) void gemm_bt_f32(const u16* __restrict__ A,
                                                   const u16* __restrict__ Bt,
                                                   const float* __restrict__ bias,
                                                   float* __restrict__ Cout,
                                                   int M, int N, int K) {
    __shared__ __align__(16) u16 As[128 * 32];
    __shared__ __align__(16) u16 Bs[128 * 32];
    int tid = threadIdx.x;
    int w = tid >> 6, lane = tid & 63, quad = lane >> 4, l16 = lane & 15;
    int m0 = blockIdx.x * 128;
    int n0 = blockIdx.y * 128;
    int wm = (w & 1) * 64, wn = (w >> 1) * 64;

    f32x4 acc[4][4] = {};
    const u16* ga = A + (long long)m0 * K;
    const u16* gb = Bt + (long long)n0 * K;

    for (int k0 = 0; k0 < K; k0 += 32) {
#pragma unroll
        for (int rr = 0; rr < 2; ++rr) {
            int c = tid + rr * 256;
            int row = c >> 2, kc = c & 3;
            async16(ga + (long long)row * K + k0 + kc * 8, (char*)As + c * 16);
            async16(gb + (long long)row * K + k0 + kc * 8, (char*)Bs + c * 16);
        }
        __syncthreads();
        bf16x8 af[4], bfv[4];
#pragma unroll
        for (int mt = 0; mt < 4; ++mt)
            af[mt] = *(const bf16x8*)(As + (wm + mt * 16 + l16) * 32 + quad * 8);
#pragma unroll
        for (int nt = 0; nt < 4; ++nt)
            bfv[nt] = *(const bf16x8*)(Bs + (wn + nt * 16 + l16) * 32 + quad * 8);
#pragma unroll
        for (int mt = 0; mt < 4; ++mt)
#pragma unroll
            for (int nt = 0; nt < 4; ++nt)
                acc[mt][nt] = __builtin_amdgcn_mfma_f32_16x16x32_bf16(af[mt], bfv[nt],
                                                                      acc[mt][nt], 0, 0, 0);
        __syncthreads();
    }

#pragma unroll
    for (int mt = 0; mt < 4; ++mt) {
#pragma unroll
        for (int nt = 0; nt < 4; ++nt) {
            int col = n0 + wn + nt * 16 + l16;
            float bvs = bias[col];
#pragma unroll
            for (int r = 0; r < 4; ++r) {
                int row = m0 + wm + mt * 16 + quad * 4 + r;
                Cout[(long long)row * N + col] = acc[mt][nt][r] + bvs;
            }
        }
    }
}

// ---------------- Flash attention, causal, S^T layout, paired q-tiles ----------------
// grid = B * NHEAD * 16; block = 256 (4 waves, 16 q-rows each); tiles (pi, 31-pi)
__global__ __launch_bounds__(256) void flash_attn(const u16* __restrict__ Q,
                                                  const u16* __restrict__ K,
                                                  const u16* __restrict__ VT,
                                                  u16* __restrict__ Y) {
    int bid = blockIdx.x;
    int pi = bid & 15;
    int h = (bid >> 4) & 31;
    int b = bid >> 9;
    int tid = threadIdx.x;
    int w = tid >> 6, lane = tid & 63, quad = lane >> 4, l16 = lane & 15;

    __shared__ __align__(16) u16 Kl[64 * 64];        // [kc][d], chunk-xor-swizzled
    __shared__ __align__(16) u16 Vl[64 * 64];        // [d][kc], chunk-xor-swizzled
    __shared__ __align__(16) u16 Pl[4][16 * 72];     // per-wave [q][kc], stride 72

    const u16* kbase = K + ((long long)(b * S_LEN)) * DM + h * DHEAD;
    const u16* vbase = VT + ((long long)((b * NHEAD + h) * DHEAD)) * S_LEN;

#pragma unroll 1
    for (int rep = 0; rep < 2; ++rep) {
        int qt = rep ? 31 - pi : pi;
        int qrow = qt * 64 + w * 16 + l16;
        const u16* qp = Q + ((long long)(b * S_LEN + qrow)) * DM + h * DHEAD + quad * 8;
        bf16x8 aq0 = *(const bf16x8*)(qp);
        bf16x8 aq1 = *(const bf16x8*)(qp + 32);

        f32x4 o[4] = {};
        float m_r = -__builtin_inff(), l_r = 0.f;

        for (int kt = 0; kt <= qt; ++kt) {
            int k0 = kt * 64;
            // ---- stage K [kc][d] and V^T [d][kc], xor-swizzled chunks ----
#pragma unroll
            for (int rr = 0; rr < 2; ++rr) {
                int c = tid + rr * 256;            // 512 chunks of 16B each
                int row = c >> 3;
                int lc = (c & 7) ^ (row & 7);      // logical 8-u16 chunk in this row
                async16(kbase + (long long)(k0 + row) * DM + lc * 8, (char*)Kl + c * 16);
                async16(vbase + (long long)row * S_LEN + k0 + lc * 8, (char*)Vl + c * 16);
            }
            __syncthreads();

            // ---- S^T = K Q^T : rows kc (regs), cols q = l16 ----
            f32x4 s[4];
#pragma unroll
            for (int nt = 0; nt < 4; ++nt) {
                int row = nt * 16 + l16;
                int sw0 = (quad ^ (row & 7)) * 8;
                int sw1 = ((quad + 4) ^ (row & 7)) * 8;
                bf16x8 ak0 = *(const bf16x8*)(Kl + row * 64 + sw0);
                bf16x8 ak1 = *(const bf16x8*)(Kl + row * 64 + sw1);
                f32x4 a = {};
                a = __builtin_amdgcn_mfma_f32_16x16x32_bf16(ak0, aq0, a, 0, 0, 0);
                a = __builtin_amdgcn_mfma_f32_16x16x32_bf16(ak1, aq1, a, 0, 0, 0);
                s[nt] = a;
            }
            // causal mask (diagonal tile only); entry (kc, q=l16)
            if (kt == qt) {
                int qg = qt * 64 + w * 16 + l16;
#pragma unroll
                for (int nt = 0; nt < 4; ++nt) {
#pragma unroll
                    for (int r = 0; r < 4; ++r) {
                        int kc = k0 + nt * 16 + quad * 4 + r;
                        if (kc > qg) s[nt][r] = -__builtin_inff();
                    }
                }
            }
            // ---- per-lane online softmax (row q = l16, replicated over quads) ----
            float mx = s[0][0];
#pragma unroll
            for (int nt = 0; nt < 4; ++nt)
#pragma unroll
                for (int r = 0; r < 4; ++r) mx = fmaxf(mx, s[nt][r]);
            mx = fmaxf(mx, __shfl_xor(mx, 16, 64));
            mx = fmaxf(mx, __shfl_xor(mx, 32, 64));
            float mnew = fmaxf(m_r, mx);
            float alpha = __expf(m_r - mnew);
            m_r = mnew;
#pragma unroll
            for (int nt = 0; nt < 4; ++nt)
#pragma unroll
                for (int r = 0; r < 4; ++r) s[nt][r] = __expf(s[nt][r] - mnew);
            float sum = 0.f;
#pragma unroll
            for (int nt = 0; nt < 4; ++nt)
#pragma unroll
                for (int r = 0; r < 4; ++r) sum += s[nt][r];
            sum += __shfl_xor(sum, 16, 64);
            sum += __shfl_xor(sum, 32, 64);
            l_r = l_r * alpha + sum;

            // redistribute alpha to o's rows (o row = quad*4+r, alpha lives at l16=row)
            float al[4];
#pragma unroll
            for (int r = 0; r < 4; ++r)
                al[r] = __shfl(alpha, (lane & 48) | (quad * 4 + r), 64);
#pragma unroll
            for (int dt = 0; dt < 4; ++dt)
#pragma unroll
                for (int r = 0; r < 4; ++r) o[dt][r] *= al[r];

            // ---- P[q=l16][kc] pack: 4x ds_write_b64, per-wave buffer, no barrier ----
            u16* pw = &Pl[w][0];
#pragma unroll
            for (int nt = 0; nt < 4; ++nt) {
                ushort4 pk;
                pk.x = f2bf(s[nt][0]); pk.y = f2bf(s[nt][1]);
                pk.z = f2bf(s[nt][2]); pk.w = f2bf(s[nt][3]);
                *(ushort4*)(pw + l16 * 72 + nt * 16 + quad * 4) = pk;
            }
            bf16x8 ap0 = *(const bf16x8*)(pw + l16 * 72 + quad * 8);
            bf16x8 ap1 = *(const bf16x8*)(pw + l16 * 72 + 32 + quad * 8);
#pragma unroll
            for (int dt = 0; dt < 4; ++dt) {
                int row = dt * 16 + l16;
                int sw0 = (quad ^ (row & 7)) * 8;
                int sw1 = ((quad + 4) ^ (row & 7)) * 8;
                bf16x8 bv0 = *(const bf16x8*)(Vl + row * 64 + sw0);
                bf16x8 bv1 = *(const bf16x8*)(Vl + row * 64 + sw1);
                o[dt] = __builtin_amdgcn_mfma_f32_16x16x32_bf16(ap0, bv0, o[dt], 0, 0, 0);
                o[dt] = __builtin_amdgcn_mfma_f32_16x16x32_bf16(ap1, bv1, o[dt], 0, 0, 0);
            }
            __syncthreads();
        }

        // ---- epilogue: o row = quad*4+r, l lives at l16=row -> 4 shuffles ----
        float li[4];
#pragma unroll
        for (int r = 0; r < 4; ++r)
            li[r] = __shfl(l_r, (lane & 48) | (quad * 4 + r), 64);
#pragma unroll
        for (int dt = 0; dt < 4; ++dt) {
#pragma unroll
            for (int r = 0; r < 4; ++r) {
                int qg = qt * 64 + w * 16 + quad * 4 + r;
                Y[((long long)(b * S_LEN + qg)) * DM + h * DHEAD + dt * 16 + l16] =
                    f2bf(o[dt][r] / li[r]);
            }
        }
    }
}

extern "C" void kernel_launch(void* const* d_in, const int* in_sizes, int n_in,
                              void* d_out, int out_size, void* d_ws, size_t ws_size,
                              hipStream_t stream) {
    const float* x  = (const float*)d_in[0];
    const float* Wq = (const float*)d_in[1];
    const float* bq = (const float*)d_in[2];
    const float* Wk = (const float*)d_in[3];
    const float* bk = (const float*)d_in[4];
    const float* Wv = (const float*)d_in[5];
    const float* bv = (const float*)d_in[6];
    const float* Wo = (const float*)d_in[7];
    const float* bo = (const float*)d_in[8];

    const long long M = 2LL * S_LEN;          // 4096
    const long long NX = M * DM;              // 8388608
    const long long NW = (long long)DM * DM;  // 4194304

    char* ws = (char*)d_ws;
    u16* xb   = (u16*)(ws);                        // 16 MB (reused as VsigT later)
    u16* Wqkv = (u16*)(ws + 16 * 1024 * 1024);     // 24 MB
    u16* Wob  = (u16*)(ws + 40 * 1024 * 1024);     // 8 MB
    u16* Qb   = (u16*)(ws + 48 * 1024 * 1024);     // 16 MB each
    u16* Kb   = (u16*)(ws + 64 * 1024 * 1024);
    u16* Vb   = (u16*)(ws + 80 * 1024 * 1024);
    u16* Yb   = (u16*)(ws + 96 * 1024 * 1024);
    u16* VTb  = xb;                                // reuse after QKV GEMM

    cast_kernel<<<(int)(NX / 1024), 256, 0, stream>>>(x, xb, NX);
    cast_kernel<<<(int)(NW / 1024), 256, 0, stream>>>(Wq, Wqkv, NW);
    cast_kernel<<<(int)(NW / 1024), 256, 0, stream>>>(Wk, Wqkv + NW, NW);
    cast_kernel<<<(int)(NW / 1024), 256, 0, stream>>>(Wv, Wqkv + 2 * NW, NW);
    cast_kernel<<<(int)(NW / 1024), 256, 0, stream>>>(Wo, Wob, NW);

    dim3 gqkv(32, 48);
    gemm_qkv<<<gqkv, 256, 0, stream>>>(xb, Wqkv, bq, bk, bv, Qb, Kb, Vb, (int)M, DM);

    rope_kernel<<<16384, 256, 0, stream>>>(Qb, 0.125f);
    rope_kernel<<<16384, 256, 0, stream>>>(Kb, 1.0f);

    vsigt_kernel<<<2048, 256, 0, stream>>>(Vb, VTb);

    flash_attn<<<2 * NHEAD * 16, 256, 0, stream>>>(Qb, Kb, VTb, Yb);

    dim3 gg(32, 16);
    gemm_bt_f32<<<gg, 256, 0, stream>>>(Yb, Wob, bo, (float*)d_out, (int)M, DM, DM);
}

// Round 3
// 459.014 us; speedup vs baseline: 1.6294x; 1.0248x over previous
//
#include <hip/hip_runtime.h>

typedef unsigned short u16;
typedef float f32x4 __attribute__((ext_vector_type(4)));
typedef __bf16 bf16x8 __attribute__((ext_vector_type(8)));

#define S_LEN 2048
#define DM 2048
#define NHEAD 32
#define DHEAD 64

__device__ __forceinline__ u16 f2bf(float f) {
    __bf16 b = (__bf16)f;
    return __builtin_bit_cast(u16, b);
}
__device__ __forceinline__ float bf2f(u16 u) {
    return (float)__builtin_bit_cast(__bf16, u);
}
// async global->LDS, 16B per lane. LDS dest must be wave-uniform base + lane*16.
__device__ __forceinline__ void async16(const void* g, void* l) {
    __builtin_amdgcn_global_load_lds(
        (const __attribute__((address_space(1))) unsigned int*)g,
        (__attribute__((address_space(3))) unsigned int*)l, 16, 0, 0);
}

// ---------------- cast f32 -> bf16 (4 elems/thread) ----------------
__global__ __launch_bounds__(256) void cast_kernel(const float* __restrict__ in,
                                                   u16* __restrict__ out, long long n) {
    long long i = ((long long)blockIdx.x * 256 + threadIdx.x) * 4;
    if (i + 3 < n) {
        float4 f = *(const float4*)(in + i);
        ushort4 v;
        v.x = f2bf(f.x); v.y = f2bf(f.y); v.z = f2bf(f.z); v.w = f2bf(f.w);
        *(ushort4*)(out + i) = v;
    }
}

// ---------------- merged QKV GEMM: A[4096][2048] x Wqkv[6144][2048]^T ----------------
// Fused epilogue: RoPE(+scale) for Q/K; sigmoid + [b,h,d,s] transpose for V.
__global__ __launch_bounds__(256) void gemm_qkv(const u16* __restrict__ A,
                                                const u16* __restrict__ Bt,
                                                const float* __restrict__ bq,
                                                const float* __restrict__ bk,
                                                const float* __restrict__ bv,
                                                u16* __restrict__ Qo, u16* __restrict__ Ko,
                                                u16* __restrict__ VTo, int M, int K) {
    __shared__ __align__(16) u16 As[128 * 32];
    __shared__ __align__(16) u16 Bs[128 * 32];
    int tid = threadIdx.x;
    int w = tid >> 6, lane = tid & 63, quad = lane >> 4, l16 = lane & 15;
    int m0 = blockIdx.x * 128;
    int n0 = blockIdx.y * 128;       // 0..6143
    int sel = n0 >> 11;
    int nloc = n0 & 2047;
    int wm = (w & 1) * 64, wn = (w >> 1) * 64;

    f32x4 acc[4][4] = {};
    const u16* ga = A + (long long)m0 * K;
    const u16* gb = Bt + (long long)n0 * K;

    for (int k0 = 0; k0 < K; k0 += 32) {
#pragma unroll
        for (int rr = 0; rr < 2; ++rr) {
            int c = tid + rr * 256;
            int row = c >> 2, kc = c & 3;
            async16(ga + (long long)row * K + k0 + kc * 8, (char*)As + c * 16);
            async16(gb + (long long)row * K + k0 + kc * 8, (char*)Bs + c * 16);
        }
        __syncthreads();
        bf16x8 af[4], bfv[4];
#pragma unroll
        for (int mt = 0; mt < 4; ++mt)
            af[mt] = *(const bf16x8*)(As + (wm + mt * 16 + l16) * 32 + quad * 8);
#pragma unroll
        for (int nt = 0; nt < 4; ++nt)
            bfv[nt] = *(const bf16x8*)(Bs + (wn + nt * 16 + l16) * 32 + quad * 8);
#pragma unroll
        for (int mt = 0; mt < 4; ++mt)
#pragma unroll
            for (int nt = 0; nt < 4; ++nt)
                acc[mt][nt] = __builtin_amdgcn_mfma_f32_16x16x32_bf16(af[mt], bfv[nt],
                                                                      acc[mt][nt], 0, 0, 0);
        __syncthreads();
    }

    if (sel < 2) {
        // ---- RoPE + scale epilogue (Q: scale 1/8, K: scale 1) ----
        float scale = sel == 0 ? 0.125f : 1.0f;
        u16* out = sel == 0 ? Qo : Ko;
        const float* bias = sel == 0 ? bq : bk;
#pragma unroll
        for (int ntl = 0; ntl < 2; ++ntl) {
            int col = nloc + wn + ntl * 16 + l16;
            int j = (wn + ntl * 16 + l16) & 63;    // 0..31
            float inv = __expf(-(float)j * 0.28782313662425575f);  // ln(1e4)/32
            float ci, si;
            sincosf(inv, &si, &ci);
            float b1 = bias[col], b2 = bias[col + 32];
#pragma unroll
            for (int mt = 0; mt < 4; ++mt) {
                int rowb = m0 + wm + mt * 16 + quad * 4;
                int s0 = rowb & (S_LEN - 1);
                float sn, cs;
                sincosf((float)s0 * inv, &sn, &cs);
#pragma unroll
                for (int r = 0; r < 4; ++r) {
                    int row = rowb + r;
                    float x1 = acc[mt][ntl][r] + b1;
                    float x2 = acc[mt][ntl + 2][r] + b2;
                    out[(long long)row * 2048 + col] = f2bf((x1 * cs - x2 * sn) * scale);
                    out[(long long)row * 2048 + col + 32] = f2bf((x2 * cs + x1 * sn) * scale);
                    float c2 = cs * ci - sn * si;    // advance angle by inv
                    float s2 = sn * ci + cs * si;
                    cs = c2; sn = s2;
                }
            }
        }
    } else {
        // ---- sigmoid + transposed store: VT[((b*32+h)*64+d)*2048 + s] ----
#pragma unroll
        for (int mt = 0; mt < 4; ++mt) {
            int rowb = m0 + wm + mt * 16 + quad * 4;
            int b = rowb >> 11;
            int s0 = rowb & (S_LEN - 1);
#pragma unroll
            for (int nt = 0; nt < 4; ++nt) {
                int col = nloc + wn + nt * 16 + l16;
                int h = col >> 6, d = col & 63;
                float bvs = bv[col];
                ushort4 pk;
                float v0 = acc[mt][nt][0] + bvs;
                float v1 = acc[mt][nt][1] + bvs;
                float v2 = acc[mt][nt][2] + bvs;
                float v3 = acc[mt][nt][3] + bvs;
                pk.x = f2bf(1.f / (1.f + __expf(-v0)));
                pk.y = f2bf(1.f / (1.f + __expf(-v1)));
                pk.z = f2bf(1.f / (1.f + __expf(-v2)));
                pk.w = f2bf(1.f / (1.f + __expf(-v3)));
                *(ushort4*)(VTo + ((long long)((b * NHEAD + h) * DHEAD + d)) * S_LEN + s0) = pk;
            }
        }
    }
}

// ---------------- GEMM: C[M][N] = A[M][K] * Bt[N][K]^T + bias (f32 out) ----------------
__global__ __launch_bounds__(256) void gemm_bt_f32(const u16* __restrict__ A,
                                                   const u16* __restrict__ Bt,
                                                   const float* __restrict__ bias,
                                                   float* __restrict__ Cout,
                                                   int M, int N, int K) {
    __shared__ __align__(16) u16 As[128 * 32];
    __shared__ __align__(16) u16 Bs[128 * 32];
    int tid = threadIdx.x;
    int w = tid >> 6, lane = tid & 63, quad = lane >> 4, l16 = lane & 15;
    int m0 = blockIdx.x * 128;
    int n0 = blockIdx.y * 128;
    int wm = (w & 1) * 64, wn = (w >> 1) * 64;

    f32x4 acc[4][4] = {};
    const u16* ga = A + (long long)m0 * K;
    const u16* gb = Bt + (long long)n0 * K;

    for (int k0 = 0; k0 < K; k0 += 32) {
#pragma unroll
        for (int rr = 0; rr < 2; ++rr) {
            int c = tid + rr * 256;
            int row = c >> 2, kc = c & 3;
            async16(ga + (long long)row * K + k0 + kc * 8, (char*)As + c * 16);
            async16(gb + (long long)row * K + k0 + kc * 8, (char*)Bs + c * 16);
        }
        __syncthreads();
        bf16x8 af[4], bfv[4];
#pragma unroll
        for (int mt = 0; mt < 4; ++mt)
            af[mt] = *(const bf16x8*)(As + (wm + mt * 16 + l16) * 32 + quad * 8);
#pragma unroll
        for (int nt = 0; nt < 4; ++nt)
            bfv[nt] = *(const bf16x8*)(Bs + (wn + nt * 16 + l16) * 32 + quad * 8);
#pragma unroll
        for (int mt = 0; mt < 4; ++mt)
#pragma unroll
            for (int nt = 0; nt < 4; ++nt)
                acc[mt][nt] = __builtin_amdgcn_mfma_f32_16x16x32_bf16(af[mt], bfv[nt],
                                                                      acc[mt][nt], 0, 0, 0);
        __syncthreads();
    }

#pragma unroll
    for (int mt = 0; mt < 4; ++mt) {
#pragma unroll
        for (int nt = 0; nt < 4; ++nt) {
            int col = n0 + wn + nt * 16 + l16;
            float bvs = bias[col];
#pragma unroll
            for (int r = 0; r < 4; ++r) {
                int row = m0 + wm + mt * 16 + quad * 4 + r;
                Cout[(long long)row * N + col] = acc[mt][nt][r] + bvs;
            }
        }
    }
}

// ---------------- Flash attention, causal, pipelined, O^T accumulation ----------------
// grid = B * NHEAD * 16; block = 256 (4 waves, 16 q-rows each); tiles (pi, 31-pi)
__global__ __launch_bounds__(256, 4) void flash_attn(const u16* __restrict__ Q,
                                                     const u16* __restrict__ K,
                                                     const u16* __restrict__ VT,
                                                     u16* __restrict__ Y) {
    int bid = blockIdx.x;
    int pi = bid & 15;
    int h = (bid >> 4) & 31;
    int b = bid >> 9;
    int tid = threadIdx.x;
    int w = tid >> 6, lane = tid & 63, quad = lane >> 4, l16 = lane & 15;

    __shared__ __align__(16) u16 Kl[64 * 64];        // [kc][d], chunk-xor-swizzled
    __shared__ __align__(16) u16 Vl[64 * 64];        // [d][kc], chunk-xor-swizzled
    __shared__ __align__(16) u16 Pl[4][16 * 72];     // per-wave [q][kc], stride 72

    const u16* kbase = K + ((long long)(b * S_LEN)) * DM + h * DHEAD;
    const u16* vbase = VT + ((long long)((b * NHEAD + h) * DHEAD)) * S_LEN;

    // prefetch registers (tile staged via regs -> LDS two-stage pipeline)
    bf16x8 kpre[2], vpre[2];
    int c0 = tid, c1 = tid + 256;
    int row0 = c0 >> 3, lc0 = (c0 & 7) ^ (row0 & 7);
    int row1 = c1 >> 3, lc1 = (c1 & 7) ^ (row1 & 7);

    // preload tile 0
    {
        kpre[0] = *(const bf16x8*)(kbase + (long long)row0 * DM + lc0 * 8);
        vpre[0] = *(const bf16x8*)(vbase + (long long)row0 * S_LEN + lc0 * 8);
        kpre[1] = *(const bf16x8*)(kbase + (long long)row1 * DM + lc1 * 8);
        vpre[1] = *(const bf16x8*)(vbase + (long long)row1 * S_LEN + lc1 * 8);
    }

#pragma unroll 1
    for (int rep = 0; rep < 2; ++rep) {
        int qt = rep ? 31 - pi : pi;
        int qrow = qt * 64 + w * 16 + l16;
        const u16* qp = Q + ((long long)(b * S_LEN + qrow)) * DM + h * DHEAD + quad * 8;
        bf16x8 aq0 = *(const bf16x8*)(qp);
        bf16x8 aq1 = *(const bf16x8*)(qp + 32);

        f32x4 o[4] = {};
        float m_r = -__builtin_inff(), l_r = 0.f;

#pragma unroll 1
        for (int kt = 0; kt <= qt; ++kt) {
            int k0 = kt * 64;
            __syncthreads();                 // all waves done reading previous tile
            // commit prefetched tile to LDS
            *(bf16x8*)((char*)Kl + c0 * 16) = kpre[0];
            *(bf16x8*)((char*)Vl + c0 * 16) = vpre[0];
            *(bf16x8*)((char*)Kl + c1 * 16) = kpre[1];
            *(bf16x8*)((char*)Vl + c1 * 16) = vpre[1];
            // issue prefetch of next tile (next rep starts at kt=0)
            {
                int nk0 = (kt < qt ? kt + 1 : 0) * 64;
                kpre[0] = *(const bf16x8*)(kbase + (long long)(nk0 + row0) * DM + lc0 * 8);
                vpre[0] = *(const bf16x8*)(vbase + (long long)row0 * S_LEN + nk0 + lc0 * 8);
                kpre[1] = *(const bf16x8*)(kbase + (long long)(nk0 + row1) * DM + lc1 * 8);
                vpre[1] = *(const bf16x8*)(vbase + (long long)row1 * S_LEN + nk0 + lc1 * 8);
            }
            __syncthreads();                 // LDS tile visible

            // ---- S^T = K Q^T : rows kc (regs), cols q = l16 ----
            f32x4 s[4];
#pragma unroll
            for (int nt = 0; nt < 4; ++nt) {
                int row = nt * 16 + l16;
                int sw0 = (quad ^ (row & 7)) * 8;
                int sw1 = ((quad + 4) ^ (row & 7)) * 8;
                bf16x8 ak0 = *(const bf16x8*)(Kl + row * 64 + sw0);
                bf16x8 ak1 = *(const bf16x8*)(Kl + row * 64 + sw1);
                f32x4 a = {};
                a = __builtin_amdgcn_mfma_f32_16x16x32_bf16(ak0, aq0, a, 0, 0, 0);
                a = __builtin_amdgcn_mfma_f32_16x16x32_bf16(ak1, aq1, a, 0, 0, 0);
                s[nt] = a;
            }
            // causal mask (diagonal tile only); entry (kc, q=l16)
            if (kt == qt) {
                int qg = qt * 64 + w * 16 + l16;
#pragma unroll
                for (int nt = 0; nt < 4; ++nt) {
#pragma unroll
                    for (int r = 0; r < 4; ++r) {
                        int kc = k0 + nt * 16 + quad * 4 + r;
                        if (kc > qg) s[nt][r] = -__builtin_inff();
                    }
                }
            }
            // ---- per-lane online softmax (row q = l16, replicated over quads) ----
            float mx = s[0][0];
#pragma unroll
            for (int nt = 0; nt < 4; ++nt)
#pragma unroll
                for (int r = 0; r < 4; ++r) mx = fmaxf(mx, s[nt][r]);
            mx = fmaxf(mx, __shfl_xor(mx, 16, 64));
            mx = fmaxf(mx, __shfl_xor(mx, 32, 64));
            float mnew = fmaxf(m_r, mx);
            float alpha = __expf(m_r - mnew);
            m_r = mnew;
#pragma unroll
            for (int nt = 0; nt < 4; ++nt)
#pragma unroll
                for (int r = 0; r < 4; ++r) s[nt][r] = __expf(s[nt][r] - mnew);
            float sum = 0.f;
#pragma unroll
            for (int nt = 0; nt < 4; ++nt)
#pragma unroll
                for (int r = 0; r < 4; ++r) sum += s[nt][r];
            sum += __shfl_xor(sum, 16, 64);
            sum += __shfl_xor(sum, 32, 64);
            l_r = l_r * alpha + sum;

            // O^T rows d, cols q=l16 -> alpha is per-lane uniform
#pragma unroll
            for (int dt = 0; dt < 4; ++dt)
#pragma unroll
                for (int r = 0; r < 4; ++r) o[dt][r] *= alpha;

            // ---- P[q=l16][kc] pack: 4x ds_write_b64, per-wave buffer, no barrier ----
            u16* pw = &Pl[w][0];
#pragma unroll
            for (int nt = 0; nt < 4; ++nt) {
                ushort4 pk;
                pk.x = f2bf(s[nt][0]); pk.y = f2bf(s[nt][1]);
                pk.z = f2bf(s[nt][2]); pk.w = f2bf(s[nt][3]);
                *(ushort4*)(pw + l16 * 72 + nt * 16 + quad * 4) = pk;
            }
            // P as B-fragment [n=q=l16][k=quad*8+j]
            bf16x8 bp0 = *(const bf16x8*)(pw + l16 * 72 + quad * 8);
            bf16x8 bp1 = *(const bf16x8*)(pw + l16 * 72 + 32 + quad * 8);
            // V^T as A-fragment [m=d][k=kc]: O^T[d][q] += V'[d][kc] P[q][kc]
#pragma unroll
            for (int dt = 0; dt < 4; ++dt) {
                int row = dt * 16 + l16;
                int sw0 = (quad ^ (row & 7)) * 8;
                int sw1 = ((quad + 4) ^ (row & 7)) * 8;
                bf16x8 av0 = *(const bf16x8*)(Vl + row * 64 + sw0);
                bf16x8 av1 = *(const bf16x8*)(Vl + row * 64 + sw1);
                o[dt] = __builtin_amdgcn_mfma_f32_16x16x32_bf16(av0, bp0, o[dt], 0, 0, 0);
                o[dt] = __builtin_amdgcn_mfma_f32_16x16x32_bf16(av1, bp1, o[dt], 0, 0, 0);
            }
        }

        // ---- epilogue: o[dt] holds O^T[d=dt*16+quad*4+r][q=l16]; l_r per-lane ----
        float inv_l = 1.f / l_r;
        u16* yp = Y + ((long long)(b * S_LEN + qt * 64 + w * 16 + l16)) * DM + h * DHEAD;
#pragma unroll
        for (int dt = 0; dt < 4; ++dt) {
            ushort4 yk;
            yk.x = f2bf(o[dt][0] * inv_l);
            yk.y = f2bf(o[dt][1] * inv_l);
            yk.z = f2bf(o[dt][2] * inv_l);
            yk.w = f2bf(o[dt][3] * inv_l);
            *(ushort4*)(yp + dt * 16 + quad * 4) = yk;
        }
    }
}

extern "C" void kernel_launch(void* const* d_in, const int* in_sizes, int n_in,
                              void* d_out, int out_size, void* d_ws, size_t ws_size,
                              hipStream_t stream) {
    const float* x  = (const float*)d_in[0];
    const float* Wq = (const float*)d_in[1];
    const float* bq = (const float*)d_in[2];
    const float* Wk = (const float*)d_in[3];
    const float* bk = (const float*)d_in[4];
    const float* Wv = (const float*)d_in[5];
    const float* bv = (const float*)d_in[6];
    const float* Wo = (const float*)d_in[7];
    const float* bo = (const float*)d_in[8];

    const long long M = 2LL * S_LEN;          // 4096
    const long long NX = M * DM;              // 8388608
    const long long NW = (long long)DM * DM;  // 4194304

    char* ws = (char*)d_ws;
    u16* xb   = (u16*)(ws);                        // 16 MB
    u16* Wqkv = (u16*)(ws + 16 * 1024 * 1024);     // 24 MB
    u16* Wob  = (u16*)(ws + 40 * 1024 * 1024);     // 8 MB
    u16* Qb   = (u16*)(ws + 48 * 1024 * 1024);     // 16 MB each
    u16* Kb   = (u16*)(ws + 64 * 1024 * 1024);
    u16* VTb  = (u16*)(ws + 80 * 1024 * 1024);     // sigmoid(V)^T [b,h,d,s]
    u16* Yb   = (u16*)(ws + 96 * 1024 * 1024);

    cast_kernel<<<(int)(NX / 1024), 256, 0, stream>>>(x, xb, NX);
    cast_kernel<<<(int)(NW / 1024), 256, 0, stream>>>(Wq, Wqkv, NW);
    cast_kernel<<<(int)(NW / 1024), 256, 0, stream>>>(Wk, Wqkv + NW, NW);
    cast_kernel<<<(int)(NW / 1024), 256, 0, stream>>>(Wv, Wqkv + 2 * NW, NW);
    cast_kernel<<<(int)(NW / 1024), 256, 0, stream>>>(Wo, Wob, NW);

    dim3 gqkv(32, 48);
    gemm_qkv<<<gqkv, 256, 0, stream>>>(xb, Wqkv, bq, bk, bv, Qb, Kb, VTb, (int)M, DM);

    flash_attn<<<2 * NHEAD * 16, 256, 0, stream>>>(Qb, Kb, VTb, Yb);

    dim3 gg(32, 16);
    gemm_bt_f32<<<gg, 256, 0, stream>>>(Yb, Wob, bo, (float*)d_out, (int)M, DM, DM);
}

// Round 5
// 452.884 us; speedup vs baseline: 1.6515x; 1.0135x over previous
//
#include <hip/hip_runtime.h>

typedef unsigned short u16;
typedef float f32x4 __attribute__((ext_vector_type(4)));
typedef __bf16 bf16x8 __attribute__((ext_vector_type(8)));

#define S_LEN 2048
#define DM 2048
#define NHEAD 32
#define DHEAD 64

__device__ __forceinline__ u16 f2bf(float f) {
    __bf16 b = (__bf16)f;
    return __builtin_bit_cast(u16, b);
}
// async global->LDS, 16B per lane. LDS dest must be wave-uniform base + lane*16.
__device__ __forceinline__ void async16(const void* g, void* l) {
    __builtin_amdgcn_global_load_lds(
        (const __attribute__((address_space(1))) unsigned int*)g,
        (__attribute__((address_space(3))) unsigned int*)l, 16, 0, 0);
}
// hardware sin/cos: v_sin/v_cos take revolutions; fract-reduce first (ISA §3)
__device__ __forceinline__ void fast_sincos(float th, float* s, float* c) {
    float rev = th * 0.15915494309189535f;   // 1/(2*pi)
    rev = rev - floorf(rev);
    *s = __builtin_amdgcn_sinf(rev);
    *c = __builtin_amdgcn_cosf(rev);
}
__device__ __forceinline__ float fexp2(float x) { return __builtin_amdgcn_exp2f(x); }

// ---------------- fused cast f32 -> bf16 for x + 4 weights (one dispatch) ----------------
__global__ __launch_bounds__(256) void cast_all(const float* __restrict__ x,
                                                const float* __restrict__ Wq,
                                                const float* __restrict__ Wk,
                                                const float* __restrict__ Wv,
                                                const float* __restrict__ Wo,
                                                u16* __restrict__ xb,
                                                u16* __restrict__ Wqkv,
                                                u16* __restrict__ Wob) {
    int bid = blockIdx.x;
    const float* src;
    u16* dst;
    long long off;
    if (bid < 8192)       { src = x;  dst = xb;             off = (long long)bid * 1024; }
    else if (bid < 12288) { src = Wq; dst = Wqkv;           off = (long long)(bid - 8192) * 1024; }
    else if (bid < 16384) { src = Wk; dst = Wqkv + 4194304; off = (long long)(bid - 12288) * 1024; }
    else if (bid < 20480) { src = Wv; dst = Wqkv + 8388608; off = (long long)(bid - 16384) * 1024; }
    else                  { src = Wo; dst = Wob;            off = (long long)(bid - 20480) * 1024; }
    long long i = off + threadIdx.x * 4;
    float4 f = *(const float4*)(src + i);
    ushort4 v;
    v.x = f2bf(f.x); v.y = f2bf(f.y); v.z = f2bf(f.z); v.w = f2bf(f.w);
    *(ushort4*)(dst + i) = v;
}

// ---------------- merged QKV GEMM: A[4096][2048] x Wqkv[6144][2048]^T ----------------
// Fused epilogue: RoPE(+scale, +log2e for Q); sigmoid + [b,h,d,s] transpose for V.
__global__ __launch_bounds__(256) void gemm_qkv(const u16* __restrict__ A,
                                                const u16* __restrict__ Bt,
                                                const float* __restrict__ bq,
                                                const float* __restrict__ bk,
                                                const float* __restrict__ bv,
                                                u16* __restrict__ Qo, u16* __restrict__ Ko,
                                                u16* __restrict__ VTo, int M, int K) {
    __shared__ __align__(16) u16 As[128 * 32];
    __shared__ __align__(16) u16 Bs[128 * 32];
    int tid = threadIdx.x;
    int w = tid >> 6, lane = tid & 63, quad = lane >> 4, l16 = lane & 15;
    int m0 = blockIdx.x * 128;
    int n0 = blockIdx.y * 128;       // 0..6143
    int sel = n0 >> 11;
    int nloc = n0 & 2047;
    int wm = (w & 1) * 64, wn = (w >> 1) * 64;

    f32x4 acc[4][4] = {};
    const u16* ga = A + (long long)m0 * K;
    const u16* gb = Bt + (long long)n0 * K;

    for (int k0 = 0; k0 < K; k0 += 32) {
#pragma unroll
        for (int rr = 0; rr < 2; ++rr) {
            int c = tid + rr * 256;
            int row = c >> 2, kc = c & 3;
            async16(ga + (long long)row * K + k0 + kc * 8, (char*)As + c * 16);
            async16(gb + (long long)row * K + k0 + kc * 8, (char*)Bs + c * 16);
        }
        __syncthreads();
        bf16x8 af[4], bfv[4];
#pragma unroll
        for (int mt = 0; mt < 4; ++mt)
            af[mt] = *(const bf16x8*)(As + (wm + mt * 16 + l16) * 32 + quad * 8);
#pragma unroll
        for (int nt = 0; nt < 4; ++nt)
            bfv[nt] = *(const bf16x8*)(Bs + (wn + nt * 16 + l16) * 32 + quad * 8);
#pragma unroll
        for (int mt = 0; mt < 4; ++mt)
#pragma unroll
            for (int nt = 0; nt < 4; ++nt)
                acc[mt][nt] = __builtin_amdgcn_mfma_f32_16x16x32_bf16(af[mt], bfv[nt],
                                                                      acc[mt][nt], 0, 0, 0);
        __syncthreads();
    }

    if (sel < 2) {
        // ---- RoPE + scale epilogue (Q: 1/8 * log2(e) for exp2 softmax; K: 1) ----
        float scale = sel == 0 ? 0.18033688011112042f : 1.0f;
        u16* out = sel == 0 ? Qo : Ko;
        const float* bias = sel == 0 ? bq : bk;
#pragma unroll
        for (int ntl = 0; ntl < 2; ++ntl) {
            int col = nloc + wn + ntl * 16 + l16;
            int j = (ntl * 16 + l16) & 31;    // 0..31
            float inv = __expf(-(float)j * 0.28782313662425575f);  // ln(1e4)/32
            float ci, si;
            fast_sincos(inv, &si, &ci);
            float b1 = bias[col], b2 = bias[col + 32];
#pragma unroll
            for (int mt = 0; mt < 4; ++mt) {
                int rowb = m0 + wm + mt * 16 + quad * 4;
                int s0 = rowb & (S_LEN - 1);
                float sn, cs;
                fast_sincos((float)s0 * inv, &sn, &cs);
#pragma unroll
                for (int r = 0; r < 4; ++r) {
                    int row = rowb + r;
                    float x1 = acc[mt][ntl][r] + b1;
                    float x2 = acc[mt][ntl + 2][r] + b2;
                    out[(long long)row * 2048 + col] = f2bf((x1 * cs - x2 * sn) * scale);
                    out[(long long)row * 2048 + col + 32] = f2bf((x2 * cs + x1 * sn) * scale);
                    float c2 = cs * ci - sn * si;    // advance angle by inv
                    float s2 = sn * ci + cs * si;
                    cs = c2; sn = s2;
                }
            }
        }
    } else {
        // ---- sigmoid + transposed store: VT[((b*32+h)*64+d)*2048 + s] ----
#pragma unroll
        for (int mt = 0; mt < 4; ++mt) {
            int rowb = m0 + wm + mt * 16 + quad * 4;
            int b = rowb >> 11;
            int s0 = rowb & (S_LEN - 1);
#pragma unroll
            for (int nt = 0; nt < 4; ++nt) {
                int col = nloc + wn + nt * 16 + l16;
                int h = col >> 6, d = col & 63;
                float bvs = bv[col];
                ushort4 pk;
                pk.x = f2bf(1.f / (1.f + __expf(-(acc[mt][nt][0] + bvs))));
                pk.y = f2bf(1.f / (1.f + __expf(-(acc[mt][nt][1] + bvs))));
                pk.z = f2bf(1.f / (1.f + __expf(-(acc[mt][nt][2] + bvs))));
                pk.w = f2bf(1.f / (1.f + __expf(-(acc[mt][nt][3] + bvs))));
                *(ushort4*)(VTo + ((long long)((b * NHEAD + h) * DHEAD + d)) * S_LEN + s0) = pk;
            }
        }
    }
}

// ---------------- GEMM: C[M][N] = A[M][K] * Bt[N][K]^T + bias (f32 out) ----------------
__global__ __launch_bounds__(256) void gemm_bt_f32(const u16* __restrict__ A,
                                                   const u16* __restrict__ Bt,
                                                   const float* __restrict__ bias,
                                                   float* __restrict__ Cout,
                                                   int M, int N, int K) {
    __shared__ __align__(16) u16 As[128 * 32];
    __shared__ __align__(16) u16 Bs[128 * 32];
    int tid = threadIdx.x;
    int w = tid >> 6, lane = tid & 63, quad = lane >> 4, l16 = lane & 15;
    int m0 = blockIdx.x * 128;
    int n0 = blockIdx.y * 128;
    int wm = (w & 1) * 64, wn = (w >> 1) * 64;

    f32x4 acc[4][4] = {};
    const u16* ga = A + (long long)m0 * K;
    const u16* gb = Bt + (long long)n0 * K;

    for (int k0 = 0; k0 < K; k0 += 32) {
#pragma unroll
        for (int rr = 0; rr < 2; ++rr) {
            int c = tid + rr * 256;
            int row = c >> 2, kc = c & 3;
            async16(ga + (long long)row * K + k0 + kc * 8, (char*)As + c * 16);
            async16(gb + (long long)row * K + k0 + kc * 8, (char*)Bs + c * 16);
        }
        __syncthreads();
        bf16x8 af[4], bfv[4];
#pragma unroll
        for (int mt = 0; mt < 4; ++mt)
            af[mt] = *(const bf16x8*)(As + (wm + mt * 16 + l16) * 32 + quad * 8);
#pragma unroll
        for (int nt = 0; nt < 4; ++nt)
            bfv[nt] = *(const bf16x8*)(Bs + (wn + nt * 16 + l16) * 32 + quad * 8);
#pragma unroll
        for (int mt = 0; mt < 4; ++mt)
#pragma unroll
            for (int nt = 0; nt < 4; ++nt)
                acc[mt][nt] = __builtin_amdgcn_mfma_f32_16x16x32_bf16(af[mt], bfv[nt],
                                                                      acc[mt][nt], 0, 0, 0);
        __syncthreads();
    }

#pragma unroll
    for (int mt = 0; mt < 4; ++mt) {
#pragma unroll
        for (int nt = 0; nt < 4; ++nt) {
            int col = n0 + wn + nt * 16 + l16;
            float bvs = bias[col];
#pragma unroll
            for (int r = 0; r < 4; ++r) {
                int row = m0 + wm + mt * 16 + quad * 4 + r;
                Cout[(long long)row * N + col] = acc[mt][nt][r] + bvs;
            }
        }
    }
}

// ---------------- Flash attention: causal, dbuf LDS, 1 barrier/iter, exp2 ----------------
// grid = B * NHEAD * 16; block = 256 (4 waves, 16 q-rows each); tiles (pi, 31-pi)
__global__ __launch_bounds__(256, 4) void flash_attn(const u16* __restrict__ Q,
                                                     const u16* __restrict__ K,
                                                     const u16* __restrict__ VT,
                                                     u16* __restrict__ Y) {
    int bid = blockIdx.x;
    int pi = bid & 15;
    int h = (bid >> 4) & 31;
    int b = bid >> 9;
    int tid = threadIdx.x;
    int w = tid >> 6, lane = tid & 63, quad = lane >> 4, l16 = lane & 15;

    __shared__ __align__(16) u16 Kl[2][64 * 64];     // [kc][d], chunk-xor-swizzled
    __shared__ __align__(16) u16 Vl[2][64 * 64];     // [d][kc], chunk-xor-swizzled
    __shared__ __align__(16) u16 Pl[4][16 * 64];     // per-wave [q][kc], xor-swizzled

    const u16* kbase = K + ((long long)(b * S_LEN)) * DM + h * DHEAD;
    const u16* vbase = VT + ((long long)((b * NHEAD + h) * DHEAD)) * S_LEN;

    // two-stage pipeline: regs hold tile `it`, LDS holds committed tile
    bf16x8 kpre[2], vpre[2];
    int c0 = tid, c1 = tid + 256;
    int row0 = c0 >> 3, lc0 = (c0 & 7) ^ (row0 & 7);
    int row1 = c1 >> 3, lc1 = (c1 & 7) ^ (row1 & 7);

    // preload tile 0
    kpre[0] = *(const bf16x8*)(kbase + (long long)row0 * DM + lc0 * 8);
    vpre[0] = *(const bf16x8*)(vbase + (long long)row0 * S_LEN + lc0 * 8);
    kpre[1] = *(const bf16x8*)(kbase + (long long)row1 * DM + lc1 * 8);
    vpre[1] = *(const bf16x8*)(vbase + (long long)row1 * S_LEN + lc1 * 8);

    int it = 0;   // running tile counter -> LDS buffer parity (continuous across reps)
#pragma unroll 1
    for (int rep = 0; rep < 2; ++rep) {
        int qt = rep ? 31 - pi : pi;
        int qrow = qt * 64 + w * 16 + l16;
        const u16* qp = Q + ((long long)(b * S_LEN + qrow)) * DM + h * DHEAD + quad * 8;
        bf16x8 aq0 = *(const bf16x8*)(qp);
        bf16x8 aq1 = *(const bf16x8*)(qp + 32);

        f32x4 o[4] = {};
        float m_r = -__builtin_inff(), l_r = 0.f;

#pragma unroll 1
        for (int kt = 0; kt <= qt; ++kt) {
            int k0 = kt * 64;
            u16* Kb_ = Kl[it & 1];
            u16* Vb_ = Vl[it & 1];
            // commit prefetched tile to this iteration's buffer
            *(bf16x8*)((char*)Kb_ + c0 * 16) = kpre[0];
            *(bf16x8*)((char*)Vb_ + c0 * 16) = vpre[0];
            *(bf16x8*)((char*)Kb_ + c1 * 16) = kpre[1];
            *(bf16x8*)((char*)Vb_ + c1 * 16) = vpre[1];
            // issue global prefetch of the next tile (tile 0 of next rep at the seam)
            {
                int nk0 = (kt < qt ? kt + 1 : 0) * 64;
                kpre[0] = *(const bf16x8*)(kbase + (long long)(nk0 + row0) * DM + lc0 * 8);
                vpre[0] = *(const bf16x8*)(vbase + (long long)row0 * S_LEN + nk0 + lc0 * 8);
                kpre[1] = *(const bf16x8*)(kbase + (long long)(nk0 + row1) * DM + lc1 * 8);
                vpre[1] = *(const bf16x8*)(vbase + (long long)row1 * S_LEN + nk0 + lc1 * 8);
            }
            __syncthreads();     // tile visible; prev-buffer readers are past this fence

            // ---- S^T = K Q^T : rows kc (regs), cols q = l16 ----
            f32x4 s[4];
#pragma unroll
            for (int nt = 0; nt < 4; ++nt) {
                int row = nt * 16 + l16;
                int sw0 = (quad ^ (row & 7)) * 8;
                int sw1 = ((quad + 4) ^ (row & 7)) * 8;
                bf16x8 ak0 = *(const bf16x8*)(Kb_ + row * 64 + sw0);
                bf16x8 ak1 = *(const bf16x8*)(Kb_ + row * 64 + sw1);
                f32x4 a = {};
                a = __builtin_amdgcn_mfma_f32_16x16x32_bf16(ak0, aq0, a, 0, 0, 0);
                a = __builtin_amdgcn_mfma_f32_16x16x32_bf16(ak1, aq1, a, 0, 0, 0);
                s[nt] = a;
            }
            // causal mask (diagonal tile only); entry (kc, q=l16)
            if (kt == qt) {
                int qg = qt * 64 + w * 16 + l16;
#pragma unroll
                for (int nt = 0; nt < 4; ++nt) {
#pragma unroll
                    for (int r = 0; r < 4; ++r) {
                        int kc = k0 + nt * 16 + quad * 4 + r;
                        if (kc > qg) s[nt][r] = -__builtin_inff();
                    }
                }
            }
            // ---- per-lane online softmax in exp2 domain (log2e folded into Q) ----
            float mx = s[0][0];
#pragma unroll
            for (int nt = 0; nt < 4; ++nt)
#pragma unroll
                for (int r = 0; r < 4; ++r) mx = fmaxf(mx, s[nt][r]);
            mx = fmaxf(mx, __shfl_xor(mx, 16, 64));
            mx = fmaxf(mx, __shfl_xor(mx, 32, 64));
            float mnew = fmaxf(m_r, mx);
            float alpha = fexp2(m_r - mnew);
            m_r = mnew;
#pragma unroll
            for (int nt = 0; nt < 4; ++nt)
#pragma unroll
                for (int r = 0; r < 4; ++r) s[nt][r] = fexp2(s[nt][r] - mnew);
            float sum = 0.f;
#pragma unroll
            for (int nt = 0; nt < 4; ++nt)
#pragma unroll
                for (int r = 0; r < 4; ++r) sum += s[nt][r];
            sum += __shfl_xor(sum, 16, 64);
            sum += __shfl_xor(sum, 32, 64);
            l_r = l_r * alpha + sum;

            // O^T rows d, cols q=l16 -> alpha per-lane uniform
#pragma unroll
            for (int dt = 0; dt < 4; ++dt)
#pragma unroll
                for (int r = 0; r < 4; ++r) o[dt][r] *= alpha;

            // ---- P[q=l16][kc] pack, xor-swizzled, per-wave, no barrier ----
            u16* pw = &Pl[w][0];
#pragma unroll
            for (int nt = 0; nt < 4; ++nt) {
                ushort4 pk;
                pk.x = f2bf(s[nt][0]); pk.y = f2bf(s[nt][1]);
                pk.z = f2bf(s[nt][2]); pk.w = f2bf(s[nt][3]);
                int chunk = (nt * 2 + (quad >> 1)) ^ (l16 & 7);
                *(ushort4*)(pw + l16 * 64 + chunk * 8 + (quad & 1) * 4) = pk;
            }
            // P as B-fragment [n=q=l16][k=quad*8+j]
            bf16x8 bp0 = *(const bf16x8*)(pw + l16 * 64 + (quad ^ (l16 & 7)) * 8);
            bf16x8 bp1 = *(const bf16x8*)(pw + l16 * 64 + ((quad + 4) ^ (l16 & 7)) * 8);
            // V^T as A-fragment [m=d][k=kc]: O^T[d][q] += V'[d][kc] P[q][kc]
#pragma unroll
            for (int dt = 0; dt < 4; ++dt) {
                int row = dt * 16 + l16;
                int sw0 = (quad ^ (row & 7)) * 8;
                int sw1 = ((quad + 4) ^ (row & 7)) * 8;
                bf16x8 av0 = *(const bf16x8*)(Vb_ + row * 64 + sw0);
                bf16x8 av1 = *(const bf16x8*)(Vb_ + row * 64 + sw1);
                o[dt] = __builtin_amdgcn_mfma_f32_16x16x32_bf16(av0, bp0, o[dt], 0, 0, 0);
                o[dt] = __builtin_amdgcn_mfma_f32_16x16x32_bf16(av1, bp1, o[dt], 0, 0, 0);
            }
            ++it;
        }

        // ---- epilogue: o[dt] holds O^T[d=dt*16+quad*4+r][q=l16]; l_r per-lane ----
        float inv_l = 1.f / l_r;
        u16* yp = Y + ((long long)(b * S_LEN + qt * 64 + w * 16 + l16)) * DM + h * DHEAD;
#pragma unroll
        for (int dt = 0; dt < 4; ++dt) {
            ushort4 yk;
            yk.x = f2bf(o[dt][0] * inv_l);
            yk.y = f2bf(o[dt][1] * inv_l);
            yk.z = f2bf(o[dt][2] * inv_l);
            yk.w = f2bf(o[dt][3] * inv_l);
            *(ushort4*)(yp + dt * 16 + quad * 4) = yk;
        }
    }
}

extern "C" void kernel_launch(void* const* d_in, const int* in_sizes, int n_in,
                              void* d_out, int out_size, void* d_ws, size_t ws_size,
                              hipStream_t stream) {
    const float* x  = (const float*)d_in[0];
    const float* Wq = (const float*)d_in[1];
    const float* bq = (const float*)d_in[2];
    const float* Wk = (const float*)d_in[3];
    const float* bk = (const float*)d_in[4];
    const float* Wv = (const float*)d_in[5];
    const float* bv = (const float*)d_in[6];
    const float* Wo = (const float*)d_in[7];
    const float* bo = (const float*)d_in[8];

    const long long M = 2LL * S_LEN;          // 4096

    char* ws = (char*)d_ws;
    u16* xb   = (u16*)(ws);                        // 16 MB
    u16* Wqkv = (u16*)(ws + 16 * 1024 * 1024);     // 24 MB
    u16* Wob  = (u16*)(ws + 40 * 1024 * 1024);     // 8 MB
    u16* Qb   = (u16*)(ws + 48 * 1024 * 1024);     // 16 MB each
    u16* Kb   = (u16*)(ws + 64 * 1024 * 1024);
    u16* VTb  = (u16*)(ws + 80 * 1024 * 1024);     // sigmoid(V)^T [b,h,d,s]
    u16* Yb   = (u16*)(ws + 96 * 1024 * 1024);

    cast_all<<<24576, 256, 0, stream>>>(x, Wq, Wk, Wv, Wo, xb, Wqkv, Wob);

    dim3 gqkv(32, 48);
    gemm_qkv<<<gqkv, 256, 0, stream>>>(xb, Wqkv, bq, bk, bv, Qb, Kb, VTb, (int)M, DM);

    flash_attn<<<2 * NHEAD * 16, 256, 0, stream>>>(Qb, Kb, VTb, Yb);

    dim3 gg(32, 16);
    gemm_bt_f32<<<gg, 256, 0, stream>>>(Yb, Wob, bo, (float*)d_out, (int)M, DM, DM);
}

// Round 6
// 431.138 us; speedup vs baseline: 1.7348x; 1.0504x over previous
//
#include <hip/hip_runtime.h>

typedef unsigned short u16;
typedef float f32x4 __attribute__((ext_vector_type(4)));
typedef __bf16 bf16x8 __attribute__((ext_vector_type(8)));

#define S_LEN 2048
#define DM 2048
#define NHEAD 32
#define DHEAD 64

__device__ __forceinline__ u16 f2bf(float f) {
    __bf16 b = (__bf16)f;
    return __builtin_bit_cast(u16, b);
}
__device__ __forceinline__ float bf2f(u16 u) {
    return (float)__builtin_bit_cast(__bf16, u);
}
// async global->LDS, 16B per lane. LDS dest must be wave-uniform base + lane*16.
__device__ __forceinline__ void async16(const void* g, void* l) {
    __builtin_amdgcn_global_load_lds(
        (const __attribute__((address_space(1))) unsigned int*)g,
        (__attribute__((address_space(3))) unsigned int*)l, 16, 0, 0);
}
// hardware sin/cos: v_sin/v_cos take revolutions; fract-reduce first (ISA §3)
__device__ __forceinline__ void fast_sincos(float th, float* s, float* c) {
    float rev = th * 0.15915494309189535f;   // 1/(2*pi)
    rev = rev - floorf(rev);
    *s = __builtin_amdgcn_sinf(rev);
    *c = __builtin_amdgcn_cosf(rev);
}
__device__ __forceinline__ float fexp2(float x) { return __builtin_amdgcn_exp2f(x); }

// ---------------- fused cast f32 -> bf16 for x + 4 weights (one dispatch) ----------------
__global__ __launch_bounds__(256) void cast_all(const float* __restrict__ x,
                                                const float* __restrict__ Wq,
                                                const float* __restrict__ Wk,
                                                const float* __restrict__ Wv,
                                                const float* __restrict__ Wo,
                                                u16* __restrict__ xb,
                                                u16* __restrict__ Wqkv,
                                                u16* __restrict__ Wob) {
    int bid = blockIdx.x;
    const float* src;
    u16* dst;
    long long off;
    if (bid < 8192)       { src = x;  dst = xb;             off = (long long)bid * 1024; }
    else if (bid < 12288) { src = Wq; dst = Wqkv;           off = (long long)(bid - 8192) * 1024; }
    else if (bid < 16384) { src = Wk; dst = Wqkv + 4194304; off = (long long)(bid - 12288) * 1024; }
    else if (bid < 20480) { src = Wv; dst = Wqkv + 8388608; off = (long long)(bid - 16384) * 1024; }
    else                  { src = Wo; dst = Wob;            off = (long long)(bid - 20480) * 1024; }
    long long i = off + threadIdx.x * 4;
    float4 f = *(const float4*)(src + i);
    ushort4 v;
    v.x = f2bf(f.x); v.y = f2bf(f.y); v.z = f2bf(f.z); v.w = f2bf(f.w);
    *(ushort4*)(dst + i) = v;
}

// ---------------- RoPE on Q (scale 0.125*log2e folded) and K, one dispatch ----------------
__global__ __launch_bounds__(256) void rope_qk(u16* __restrict__ Qb, u16* __restrict__ Kb) {
    long long idx = (long long)blockIdx.x * 256 + threadIdx.x;   // 2 * 2^22
    int which = (int)(idx >> 22);
    int t = (int)(idx & 4194303);
    int j = t & 31;
    int h = (t >> 5) & 31;
    int row = t >> 10;                  // 0..4095
    int s = row & (S_LEN - 1);
    u16* T = which ? Kb : Qb;
    float scale = which ? 1.0f : 0.18033688011112042f;  // Q: 1/8 * log2(e)
    long long base = (long long)row * DM + h * DHEAD;
    float inv = __expf(-(float)j * 0.28782313662425575f);  // ln(1e4)/32
    float sn, cs;
    fast_sincos((float)s * inv, &sn, &cs);
    float x1 = bf2f(T[base + j]);
    float x2 = bf2f(T[base + 32 + j]);
    T[base + j] = f2bf((x1 * cs - x2 * sn) * scale);
    T[base + 32 + j] = f2bf((x2 * cs + x1 * sn) * scale);
}

// ---------------- merged QKV GEMM: A[4096][2048] x Wqkv[6144][2048]^T ----------------
// Plain bias+store for Q/K (RoPE is a separate pass); sigmoid + [b,h,d,s] transpose for V.
__global__ __launch_bounds__(256) void gemm_qkv(const u16* __restrict__ A,
                                                const u16* __restrict__ Bt,
                                                const float* __restrict__ bq,
                                                const float* __restrict__ bk,
                                                const float* __restrict__ bv,
                                                u16* __restrict__ Qo, u16* __restrict__ Ko,
                                                u16* __restrict__ VTo, int M, int K) {
    __shared__ __align__(16) u16 As[128 * 32];
    __shared__ __align__(16) u16 Bs[128 * 32];
    int tid = threadIdx.x;
    int w = tid >> 6, lane = tid & 63, quad = lane >> 4, l16 = lane & 15;
    int m0 = blockIdx.x * 128;
    int n0 = blockIdx.y * 128;       // 0..6143
    int sel = n0 >> 11;
    int nloc = n0 & 2047;
    int wm = (w & 1) * 64, wn = (w >> 1) * 64;

    f32x4 acc[4][4] = {};
    const u16* ga = A + (long long)m0 * K;
    const u16* gb = Bt + (long long)n0 * K;

    for (int k0 = 0; k0 < K; k0 += 32) {
#pragma unroll
        for (int rr = 0; rr < 2; ++rr) {
            int c = tid + rr * 256;
            int row = c >> 2, kc = c & 3;
            async16(ga + (long long)row * K + k0 + kc * 8, (char*)As + c * 16);
            async16(gb + (long long)row * K + k0 + kc * 8, (char*)Bs + c * 16);
        }
        __syncthreads();
        bf16x8 af[4], bfv[4];
#pragma unroll
        for (int mt = 0; mt < 4; ++mt)
            af[mt] = *(const bf16x8*)(As + (wm + mt * 16 + l16) * 32 + quad * 8);
#pragma unroll
        for (int nt = 0; nt < 4; ++nt)
            bfv[nt] = *(const bf16x8*)(Bs + (wn + nt * 16 + l16) * 32 + quad * 8);
#pragma unroll
        for (int mt = 0; mt < 4; ++mt)
#pragma unroll
            for (int nt = 0; nt < 4; ++nt)
                acc[mt][nt] = __builtin_amdgcn_mfma_f32_16x16x32_bf16(af[mt], bfv[nt],
                                                                      acc[mt][nt], 0, 0, 0);
        __syncthreads();
    }

    if (sel < 2) {
        u16* out = sel == 0 ? Qo : Ko;
        const float* bias = sel == 0 ? bq : bk;
#pragma unroll
        for (int mt = 0; mt < 4; ++mt) {
#pragma unroll
            for (int nt = 0; nt < 4; ++nt) {
                int col = nloc + wn + nt * 16 + l16;
                float bvs = bias[col];
#pragma unroll
                for (int r = 0; r < 4; ++r) {
                    int row = m0 + wm + mt * 16 + quad * 4 + r;
                    out[(long long)row * 2048 + col] = f2bf(acc[mt][nt][r] + bvs);
                }
            }
        }
    } else {
        // ---- sigmoid + transposed store: VT[((b*32+h)*64+d)*2048 + s] ----
#pragma unroll
        for (int mt = 0; mt < 4; ++mt) {
            int rowb = m0 + wm + mt * 16 + quad * 4;
            int b = rowb >> 11;
            int s0 = rowb & (S_LEN - 1);
#pragma unroll
            for (int nt = 0; nt < 4; ++nt) {
                int col = nloc + wn + nt * 16 + l16;
                int h = col >> 6, d = col & 63;
                float bvs = bv[col];
                ushort4 pk;
                pk.x = f2bf(1.f / (1.f + __expf(-(acc[mt][nt][0] + bvs))));
                pk.y = f2bf(1.f / (1.f + __expf(-(acc[mt][nt][1] + bvs))));
                pk.z = f2bf(1.f / (1.f + __expf(-(acc[mt][nt][2] + bvs))));
                pk.w = f2bf(1.f / (1.f + __expf(-(acc[mt][nt][3] + bvs))));
                *(ushort4*)(VTo + ((long long)((b * NHEAD + h) * DHEAD + d)) * S_LEN + s0) = pk;
            }
        }
    }
}

// ---------------- GEMM: C[M][N] = A[M][K] * Bt[N][K]^T + bias (f32 out) ----------------
__global__ __launch_bounds__(256) void gemm_bt_f32(const u16* __restrict__ A,
                                                   const u16* __restrict__ Bt,
                                                   const float* __restrict__ bias,
                                                   float* __restrict__ Cout,
                                                   int M, int N, int K) {
    __shared__ __align__(16) u16 As[128 * 32];
    __shared__ __align__(16) u16 Bs[128 * 32];
    int tid = threadIdx.x;
    int w = tid >> 6, lane = tid & 63, quad = lane >> 4, l16 = lane & 15;
    int m0 = blockIdx.x * 128;
    int n0 = blockIdx.y * 128;
    int wm = (w & 1) * 64, wn = (w >> 1) * 64;

    f32x4 acc[4][4] = {};
    const u16* ga = A + (long long)m0 * K;
    const u16* gb = Bt + (long long)n0 * K;

    for (int k0 = 0; k0 < K; k0 += 32) {
#pragma unroll
        for (int rr = 0; rr < 2; ++rr) {
            int c = tid + rr * 256;
            int row = c >> 2, kc = c & 3;
            async16(ga + (long long)row * K + k0 + kc * 8, (char*)As + c * 16);
            async16(gb + (long long)row * K + k0 + kc * 8, (char*)Bs + c * 16);
        }
        __syncthreads();
        bf16x8 af[4], bfv[4];
#pragma unroll
        for (int mt = 0; mt < 4; ++mt)
            af[mt] = *(const bf16x8*)(As + (wm + mt * 16 + l16) * 32 + quad * 8);
#pragma unroll
        for (int nt = 0; nt < 4; ++nt)
            bfv[nt] = *(const bf16x8*)(Bs + (wn + nt * 16 + l16) * 32 + quad * 8);
#pragma unroll
        for (int mt = 0; mt < 4; ++mt)
#pragma unroll
            for (int nt = 0; nt < 4; ++nt)
                acc[mt][nt] = __builtin_amdgcn_mfma_f32_16x16x32_bf16(af[mt], bfv[nt],
                                                                      acc[mt][nt], 0, 0, 0);
        __syncthreads();
    }

#pragma unroll
    for (int mt = 0; mt < 4; ++mt) {
#pragma unroll
        for (int nt = 0; nt < 4; ++nt) {
            int col = n0 + wn + nt * 16 + l16;
            float bvs = bias[col];
#pragma unroll
            for (int r = 0; r < 4; ++r) {
                int row = m0 + wm + mt * 16 + quad * 4 + r;
                Cout[(long long)row * N + col] = acc[mt][nt][r] + bvs;
            }
        }
    }
}

// ---------------- Flash attention: 128-row Q-tiles, dbuf LDS, 1 barrier/iter, exp2 ------
// grid = B * NHEAD * 8; block = 256 (4 waves x 32 q-rows); paired tiles (pi, 15-pi)
__global__ __launch_bounds__(256, 2) void flash_attn(const u16* __restrict__ Q,
                                                     const u16* __restrict__ K,
                                                     const u16* __restrict__ VT,
                                                     u16* __restrict__ Y) {
    int bid = blockIdx.x;
    int pi = bid & 7;
    int h = (bid >> 3) & 31;
    int b = bid >> 8;
    int tid = threadIdx.x;
    int w = tid >> 6, lane = tid & 63, quad = lane >> 4, l16 = lane & 15;

    __shared__ __align__(16) u16 Kl[2][64 * 64];     // [kc][d], chunk-xor-swizzled
    __shared__ __align__(16) u16 Vl[2][64 * 64];     // [d][kc], chunk-xor-swizzled
    __shared__ __align__(16) u16 Pl[4][32 * 64];     // per-wave [q][kc], xor-swizzled

    const u16* kbase = K + ((long long)(b * S_LEN)) * DM + h * DHEAD;
    const u16* vbase = VT + ((long long)((b * NHEAD + h) * DHEAD)) * S_LEN;

    // two-stage pipeline: regs hold next tile, LDS holds committed tile
    bf16x8 kpre[2], vpre[2];
    int c0 = tid, c1 = tid + 256;
    int row0 = c0 >> 3, lc0 = (c0 & 7) ^ (row0 & 7);
    int row1 = c1 >> 3, lc1 = (c1 & 7) ^ (row1 & 7);

    // preload k-tile 0
    kpre[0] = *(const bf16x8*)(kbase + (long long)row0 * DM + lc0 * 8);
    vpre[0] = *(const bf16x8*)(vbase + (long long)row0 * S_LEN + lc0 * 8);
    kpre[1] = *(const bf16x8*)(kbase + (long long)row1 * DM + lc1 * 8);
    vpre[1] = *(const bf16x8*)(vbase + (long long)row1 * S_LEN + lc1 * 8);

    int it = 0;   // running tile counter -> LDS buffer parity (continuous across reps)
#pragma unroll 1
    for (int rep = 0; rep < 2; ++rep) {
        int qt = rep ? 15 - pi : pi;            // 128-row q-tile index
        // Q fragments for both 16-row sub-tiles
        bf16x8 aq[2][2];
#pragma unroll
        for (int sub = 0; sub < 2; ++sub) {
            int qrow = qt * 128 + w * 32 + sub * 16 + l16;
            const u16* qp = Q + ((long long)(b * S_LEN + qrow)) * DM + h * DHEAD + quad * 8;
            aq[sub][0] = *(const bf16x8*)(qp);
            aq[sub][1] = *(const bf16x8*)(qp + 32);
        }

        f32x4 o[2][4] = {};
        float m_r[2] = {-__builtin_inff(), -__builtin_inff()};
        float l_r[2] = {0.f, 0.f};

        int kts = 2 * qt + 2;
#pragma unroll 1
        for (int kt = 0; kt < kts; ++kt) {
            u16* Kb_ = Kl[it & 1];
            u16* Vb_ = Vl[it & 1];
            // commit prefetched tile to this iteration's buffer
            *(bf16x8*)((char*)Kb_ + c0 * 16) = kpre[0];
            *(bf16x8*)((char*)Vb_ + c0 * 16) = vpre[0];
            *(bf16x8*)((char*)Kb_ + c1 * 16) = kpre[1];
            *(bf16x8*)((char*)Vb_ + c1 * 16) = vpre[1];
            // issue global prefetch of the next tile (tile 0 of next rep at the seam)
            {
                int nk0 = (kt + 1 < kts ? kt + 1 : 0) * 64;
                kpre[0] = *(const bf16x8*)(kbase + (long long)(nk0 + row0) * DM + lc0 * 8);
                vpre[0] = *(const bf16x8*)(vbase + (long long)row0 * S_LEN + nk0 + lc0 * 8);
                kpre[1] = *(const bf16x8*)(kbase + (long long)(nk0 + row1) * DM + lc1 * 8);
                vpre[1] = *(const bf16x8*)(vbase + (long long)row1 * S_LEN + nk0 + lc1 * 8);
            }
            __syncthreads();     // tile visible; prev-buffer readers are past this fence

            // ---- K fragments (shared by both q-subtiles) ----
            bf16x8 ak0[4], ak1[4];
#pragma unroll
            for (int nt = 0; nt < 4; ++nt) {
                int row = nt * 16 + l16;
                ak0[nt] = *(const bf16x8*)(Kb_ + row * 64 + (quad ^ (row & 7)) * 8);
                ak1[nt] = *(const bf16x8*)(Kb_ + row * 64 + ((quad + 4) ^ (row & 7)) * 8);
            }

            bf16x8 bp[2][2];
            u16* pw = &Pl[w][0];
#pragma unroll
            for (int sub = 0; sub < 2; ++sub) {
                // ---- S^T = K Q^T : rows kc (regs), cols q = l16 ----
                f32x4 s[4];
#pragma unroll
                for (int nt = 0; nt < 4; ++nt) {
                    f32x4 a = {};
                    a = __builtin_amdgcn_mfma_f32_16x16x32_bf16(ak0[nt], aq[sub][0], a, 0, 0, 0);
                    a = __builtin_amdgcn_mfma_f32_16x16x32_bf16(ak1[nt], aq[sub][1], a, 0, 0, 0);
                    s[nt] = a;
                }
                // causal mask (only the last two k-tiles can touch the diagonal)
                if (kt >= 2 * qt) {
                    int qg = qt * 128 + w * 32 + sub * 16 + l16;
#pragma unroll
                    for (int nt = 0; nt < 4; ++nt) {
#pragma unroll
                        for (int r = 0; r < 4; ++r) {
                            int kg = kt * 64 + nt * 16 + quad * 4 + r;
                            if (kg > qg) s[nt][r] = -__builtin_inff();
                        }
                    }
                }
                // ---- per-lane online softmax in exp2 domain ----
                float mx = s[0][0];
#pragma unroll
                for (int nt = 0; nt < 4; ++nt)
#pragma unroll
                    for (int r = 0; r < 4; ++r) mx = fmaxf(mx, s[nt][r]);
                mx = fmaxf(mx, __shfl_xor(mx, 16, 64));
                mx = fmaxf(mx, __shfl_xor(mx, 32, 64));
                float mnew = fmaxf(m_r[sub], mx);
                float alpha = fexp2(m_r[sub] - mnew);
                m_r[sub] = mnew;
#pragma unroll
                for (int nt = 0; nt < 4; ++nt)
#pragma unroll
                    for (int r = 0; r < 4; ++r) s[nt][r] = fexp2(s[nt][r] - mnew);
                float sum = 0.f;
#pragma unroll
                for (int nt = 0; nt < 4; ++nt)
#pragma unroll
                    for (int r = 0; r < 4; ++r) sum += s[nt][r];
                sum += __shfl_xor(sum, 16, 64);
                sum += __shfl_xor(sum, 32, 64);
                l_r[sub] = l_r[sub] * alpha + sum;
#pragma unroll
                for (int dt = 0; dt < 4; ++dt)
#pragma unroll
                    for (int r = 0; r < 4; ++r) o[sub][dt][r] *= alpha;

                // ---- P[q][kc] pack, xor-swizzled, per-wave, no barrier ----
                int prow = sub * 16 + l16;
#pragma unroll
                for (int nt = 0; nt < 4; ++nt) {
                    ushort4 pk;
                    pk.x = f2bf(s[nt][0]); pk.y = f2bf(s[nt][1]);
                    pk.z = f2bf(s[nt][2]); pk.w = f2bf(s[nt][3]);
                    int chunk = (nt * 2 + (quad >> 1)) ^ (l16 & 7);
                    *(ushort4*)(pw + prow * 64 + chunk * 8 + (quad & 1) * 4) = pk;
                }
                bp[sub][0] = *(const bf16x8*)(pw + prow * 64 + (quad ^ (l16 & 7)) * 8);
                bp[sub][1] = *(const bf16x8*)(pw + prow * 64 + ((quad + 4) ^ (l16 & 7)) * 8);
            }

            // ---- V fragments (shared) + PV MFMAs ----
#pragma unroll
            for (int dt = 0; dt < 4; ++dt) {
                int row = dt * 16 + l16;
                bf16x8 av0 = *(const bf16x8*)(Vb_ + row * 64 + (quad ^ (row & 7)) * 8);
                bf16x8 av1 = *(const bf16x8*)(Vb_ + row * 64 + ((quad + 4) ^ (row & 7)) * 8);
#pragma unroll
                for (int sub = 0; sub < 2; ++sub) {
                    o[sub][dt] = __builtin_amdgcn_mfma_f32_16x16x32_bf16(av0, bp[sub][0],
                                                                         o[sub][dt], 0, 0, 0);
                    o[sub][dt] = __builtin_amdgcn_mfma_f32_16x16x32_bf16(av1, bp[sub][1],
                                                                         o[sub][dt], 0, 0, 0);
                }
            }
            ++it;
        }

        // ---- epilogue: o[sub][dt] holds O^T[d][q=l16]; l per-lane ----
#pragma unroll
        for (int sub = 0; sub < 2; ++sub) {
            float inv_l = 1.f / l_r[sub];
            u16* yp = Y + ((long long)(b * S_LEN + qt * 128 + w * 32 + sub * 16 + l16)) * DM
                      + h * DHEAD;
#pragma unroll
            for (int dt = 0; dt < 4; ++dt) {
                ushort4 yk;
                yk.x = f2bf(o[sub][dt][0] * inv_l);
                yk.y = f2bf(o[sub][dt][1] * inv_l);
                yk.z = f2bf(o[sub][dt][2] * inv_l);
                yk.w = f2bf(o[sub][dt][3] * inv_l);
                *(ushort4*)(yp + dt * 16 + quad * 4) = yk;
            }
        }
    }
}

extern "C" void kernel_launch(void* const* d_in, const int* in_sizes, int n_in,
                              void* d_out, int out_size, void* d_ws, size_t ws_size,
                              hipStream_t stream) {
    const float* x  = (const float*)d_in[0];
    const float* Wq = (const float*)d_in[1];
    const float* bq = (const float*)d_in[2];
    const float* Wk = (const float*)d_in[3];
    const float* bk = (const float*)d_in[4];
    const float* Wv = (const float*)d_in[5];
    const float* bv = (const float*)d_in[6];
    const float* Wo = (const float*)d_in[7];
    const float* bo = (const float*)d_in[8];

    const long long M = 2LL * S_LEN;          // 4096

    char* ws = (char*)d_ws;
    u16* xb   = (u16*)(ws);                        // 16 MB
    u16* Wqkv = (u16*)(ws + 16 * 1024 * 1024);     // 24 MB
    u16* Wob  = (u16*)(ws + 40 * 1024 * 1024);     // 8 MB
    u16* Qb   = (u16*)(ws + 48 * 1024 * 1024);     // 16 MB each
    u16* Kb   = (u16*)(ws + 64 * 1024 * 1024);
    u16* VTb  = (u16*)(ws + 80 * 1024 * 1024);     // sigmoid(V)^T [b,h,d,s]
    u16* Yb   = (u16*)(ws + 96 * 1024 * 1024);

    cast_all<<<24576, 256, 0, stream>>>(x, Wq, Wk, Wv, Wo, xb, Wqkv, Wob);

    dim3 gqkv(32, 48);
    gemm_qkv<<<gqkv, 256, 0, stream>>>(xb, Wqkv, bq, bk, bv, Qb, Kb, VTb, (int)M, DM);

    rope_qk<<<32768, 256, 0, stream>>>(Qb, Kb);

    flash_attn<<<2 * NHEAD * 8, 256, 0, stream>>>(Qb, Kb, VTb, Yb);

    dim3 gg(32, 16);
    gemm_bt_f32<<<gg, 256, 0, stream>>>(Yb, Wob, bo, (float*)d_out, (int)M, DM, DM);
}

// Round 7
// 415.163 us; speedup vs baseline: 1.8015x; 1.0385x over previous
//
#include <hip/hip_runtime.h>

typedef unsigned short u16;
typedef float f32x4 __attribute__((ext_vector_type(4)));
typedef __bf16 bf16x8 __attribute__((ext_vector_type(8)));

#define S_LEN 2048
#define DM 2048
#define NHEAD 32
#define DHEAD 64

__device__ __forceinline__ u16 f2bf(float f) {
    __bf16 b = (__bf16)f;
    return __builtin_bit_cast(u16, b);
}
__device__ __forceinline__ float bf2f(u16 u) {
    return (float)__builtin_bit_cast(__bf16, u);
}
// async global->LDS, 16B per lane. LDS dest must be wave-uniform base + lane*16.
__device__ __forceinline__ void async16(const void* g, void* l) {
    __builtin_amdgcn_global_load_lds(
        (const __attribute__((address_space(1))) unsigned int*)g,
        (__attribute__((address_space(3))) unsigned int*)l, 16, 0, 0);
}
// hardware sin/cos: v_sin/v_cos take revolutions; fract-reduce first (ISA §3)
__device__ __forceinline__ void fast_sincos(float th, float* s, float* c) {
    float rev = th * 0.15915494309189535f;   // 1/(2*pi)
    rev = rev - floorf(rev);
    *s = __builtin_amdgcn_sinf(rev);
    *c = __builtin_amdgcn_cosf(rev);
}
__device__ __forceinline__ float fexp2(float x) { return __builtin_amdgcn_exp2f(x); }

// ---------------- fused cast f32 -> bf16 for x + 4 weights (one dispatch) ----------------
__global__ __launch_bounds__(256) void cast_all(const float* __restrict__ x,
                                                const float* __restrict__ Wq,
                                                const float* __restrict__ Wk,
                                                const float* __restrict__ Wv,
                                                const float* __restrict__ Wo,
                                                u16* __restrict__ xb,
                                                u16* __restrict__ Wqkv,
                                                u16* __restrict__ Wob) {
    int bid = blockIdx.x;
    const float* src;
    u16* dst;
    long long off;
    if (bid < 8192)       { src = x;  dst = xb;             off = (long long)bid * 1024; }
    else if (bid < 12288) { src = Wq; dst = Wqkv;           off = (long long)(bid - 8192) * 1024; }
    else if (bid < 16384) { src = Wk; dst = Wqkv + 4194304; off = (long long)(bid - 12288) * 1024; }
    else if (bid < 20480) { src = Wv; dst = Wqkv + 8388608; off = (long long)(bid - 16384) * 1024; }
    else                  { src = Wo; dst = Wob;            off = (long long)(bid - 20480) * 1024; }
    long long i = off + threadIdx.x * 4;
    float4 f = *(const float4*)(src + i);
    ushort4 v;
    v.x = f2bf(f.x); v.y = f2bf(f.y); v.z = f2bf(f.z); v.w = f2bf(f.w);
    *(ushort4*)(dst + i) = v;
}

// ---- merged aux pass: RoPE on Q (exp2-scale folded) & K, plus sigmoid(V) transpose ----
// blocks 0..32767: rope elementwise; blocks 32768..34815: vsigt tile transpose
__global__ __launch_bounds__(256) void rope_vsig(u16* __restrict__ Qb, u16* __restrict__ Kb,
                                                 const u16* __restrict__ V,
                                                 u16* __restrict__ VT) {
    int bid = blockIdx.x;
    if (bid < 32768) {
        long long idx = (long long)bid * 256 + threadIdx.x;   // 2 * 2^22
        int which = (int)(idx >> 22);
        int t = (int)(idx & 4194303);
        int j = t & 31;
        int h = (t >> 5) & 31;
        int row = t >> 10;                  // 0..4095
        int s = row & (S_LEN - 1);
        u16* T = which ? Kb : Qb;
        float scale = which ? 1.0f : 0.18033688011112042f;  // Q: 1/8 * log2(e)
        long long base = (long long)row * DM + h * DHEAD;
        float inv = __expf(-(float)j * 0.28782313662425575f);  // ln(1e4)/32
        float sn, cs;
        fast_sincos((float)s * inv, &sn, &cs);
        float x1 = bf2f(T[base + j]);
        float x2 = bf2f(T[base + 32 + j]);
        T[base + j] = f2bf((x1 * cs - x2 * sn) * scale);
        T[base + 32 + j] = f2bf((x2 * cs + x1 * sn) * scale);
    } else {
        int vb = bid - 32768;
        int st = vb & 63;        // 64-row s-tile over 4096 rows
        int h = vb >> 6;         // head
        __shared__ u16 T[64][72];
        int r = threadIdx.x >> 2, c0 = (threadIdx.x & 3) * 16;
        const u16* src = V + (long long)(st * 64 + r) * DM + h * 64 + c0;
#pragma unroll
        for (int half = 0; half < 2; ++half) {
            bf16x8 v = *(const bf16x8*)(src + half * 8);
#pragma unroll
            for (int j = 0; j < 8; ++j) {
                float vf = (float)v[j];
                T[c0 + half * 8 + j][r] = f2bf(1.f / (1.f + __expf(-vf)));
            }
        }
        __syncthreads();
        int d = threadIdx.x >> 2, s0 = (threadIdx.x & 3) * 16;
        int b = st >> 5;
        int sl = (st & 31) * 64;
        u16* dst = VT + ((long long)((b * NHEAD + h) * DHEAD + d)) * S_LEN + sl + s0;
#pragma unroll
        for (int q = 0; q < 4; ++q)
            *(ushort4*)(dst + q * 4) = *(const ushort4*)(&T[d][s0] + q * 4);
    }
}

// ---------------- merged QKV GEMM: A[4096][2048] x Wqkv[6144][2048]^T, plain outputs ----
__global__ __launch_bounds__(256) void gemm_qkv(const u16* __restrict__ A,
                                                const u16* __restrict__ Bt,
                                                const float* __restrict__ bq,
                                                const float* __restrict__ bk,
                                                const float* __restrict__ bv,
                                                u16* __restrict__ Qo, u16* __restrict__ Ko,
                                                u16* __restrict__ Vo, int M, int K) {
    __shared__ __align__(16) u16 As[128 * 32];
    __shared__ __align__(16) u16 Bs[128 * 32];
    int tid = threadIdx.x;
    int w = tid >> 6, lane = tid & 63, quad = lane >> 4, l16 = lane & 15;
    int m0 = blockIdx.x * 128;
    int n0 = blockIdx.y * 128;       // 0..6143
    int sel = n0 >> 11;
    int nloc = n0 & 2047;
    u16* out = sel == 0 ? Qo : (sel == 1 ? Ko : Vo);
    const float* bias = sel == 0 ? bq : (sel == 1 ? bk : bv);
    int wm = (w & 1) * 64, wn = (w >> 1) * 64;

    f32x4 acc[4][4] = {};
    const u16* ga = A + (long long)m0 * K;
    const u16* gb = Bt + (long long)n0 * K;

    for (int k0 = 0; k0 < K; k0 += 32) {
#pragma unroll
        for (int rr = 0; rr < 2; ++rr) {
            int c = tid + rr * 256;
            int row = c >> 2, kc = c & 3;
            async16(ga + (long long)row * K + k0 + kc * 8, (char*)As + c * 16);
            async16(gb + (long long)row * K + k0 + kc * 8, (char*)Bs + c * 16);
        }
        __syncthreads();
        bf16x8 af[4], bfv[4];
#pragma unroll
        for (int mt = 0; mt < 4; ++mt)
            af[mt] = *(const bf16x8*)(As + (wm + mt * 16 + l16) * 32 + quad * 8);
#pragma unroll
        for (int nt = 0; nt < 4; ++nt)
            bfv[nt] = *(const bf16x8*)(Bs + (wn + nt * 16 + l16) * 32 + quad * 8);
#pragma unroll
        for (int mt = 0; mt < 4; ++mt)
#pragma unroll
            for (int nt = 0; nt < 4; ++nt)
                acc[mt][nt] = __builtin_amdgcn_mfma_f32_16x16x32_bf16(af[mt], bfv[nt],
                                                                      acc[mt][nt], 0, 0, 0);
        __syncthreads();
    }

#pragma unroll
    for (int mt = 0; mt < 4; ++mt) {
#pragma unroll
        for (int nt = 0; nt < 4; ++nt) {
            int col = nloc + wn + nt * 16 + l16;
            float bvs = bias[col];
#pragma unroll
            for (int r = 0; r < 4; ++r) {
                int row = m0 + wm + mt * 16 + quad * 4 + r;
                out[(long long)row * 2048 + col] = f2bf(acc[mt][nt][r] + bvs);
            }
        }
    }
}

// ---------------- GEMM: C[M][N] = A[M][K] * Bt[N][K]^T + bias (f32 out) ----------------
__global__ __launch_bounds__(256) void gemm_bt_f32(const u16* __restrict__ A,
                                                   const u16* __restrict__ Bt,
                                                   const float* __restrict__ bias,
                                                   float* __restrict__ Cout,
                                                   int M, int N, int K) {
    __shared__ __align__(16) u16 As[128 * 32];
    __shared__ __align__(16) u16 Bs[128 * 32];
    int tid = threadIdx.x;
    int w = tid >> 6, lane = tid & 63, quad = lane >> 4, l16 = lane & 15;
    int m0 = blockIdx.x * 128;
    int n0 = blockIdx.y * 128;
    int wm = (w & 1) * 64, wn = (w >> 1) * 64;

    f32x4 acc[4][4] = {};
    const u16* ga = A + (long long)m0 * K;
    const u16* gb = Bt + (long long)n0 * K;

    for (int k0 = 0; k0 < K; k0 += 32) {
#pragma unroll
        for (int rr = 0; rr < 2; ++rr) {
            int c = tid + rr * 256;
            int row = c >> 2, kc = c & 3;
            async16(ga + (long long)row * K + k0 + kc * 8, (char*)As + c * 16);
            async16(gb + (long long)row * K + k0 + kc * 8, (char*)Bs + c * 16);
        }
        __syncthreads();
        bf16x8 af[4], bfv[4];
#pragma unroll
        for (int mt = 0; mt < 4; ++mt)
            af[mt] = *(const bf16x8*)(As + (wm + mt * 16 + l16) * 32 + quad * 8);
#pragma unroll
        for (int nt = 0; nt < 4; ++nt)
            bfv[nt] = *(const bf16x8*)(Bs + (wn + nt * 16 + l16) * 32 + quad * 8);
#pragma unroll
        for (int mt = 0; mt < 4; ++mt)
#pragma unroll
            for (int nt = 0; nt < 4; ++nt)
                acc[mt][nt] = __builtin_amdgcn_mfma_f32_16x16x32_bf16(af[mt], bfv[nt],
                                                                      acc[mt][nt], 0, 0, 0);
        __syncthreads();
    }

#pragma unroll
    for (int mt = 0; mt < 4; ++mt) {
#pragma unroll
        for (int nt = 0; nt < 4; ++nt) {
            int col = n0 + wn + nt * 16 + l16;
            float bvs = bias[col];
#pragma unroll
            for (int r = 0; r < 4; ++r) {
                int row = m0 + wm + mt * 16 + quad * 4 + r;
                Cout[(long long)row * N + col] = acc[mt][nt][r] + bvs;
            }
        }
    }
}

// ---------------- Flash attention: 128-row Q-tiles, XCD-swizzled, dbuf LDS, exp2 --------
// grid = 512; xcd = bid&7 owns heads xcd*8..xcd*8+8 -> K/V L2-resident per XCD
__global__ __launch_bounds__(256, 2) void flash_attn(const u16* __restrict__ Q,
                                                     const u16* __restrict__ K,
                                                     const u16* __restrict__ VT,
                                                     u16* __restrict__ Y) {
    int bid = blockIdx.x;
    // XCD-aware swizzle: consecutive blockIdx round-robin over 8 XCDs; keep all 8
    // q-tile blocks of one head on the same XCD so K/V stay in that XCD's L2.
    int xcd = bid & 7;
    int idx = bid >> 3;              // 0..63
    int pi = idx & 7;                // q-tile pair index within head
    int hg = xcd * 8 + (idx >> 3);   // global head 0..63
    int b = hg >> 5, h = hg & 31;
    int tid = threadIdx.x;
    int w = tid >> 6, lane = tid & 63, quad = lane >> 4, l16 = lane & 15;

    __shared__ __align__(16) u16 Kl[2][64 * 64];     // [kc][d], chunk-xor-swizzled
    __shared__ __align__(16) u16 Vl[2][64 * 64];     // [d][kc], chunk-xor-swizzled
    __shared__ __align__(16) u16 Pl[4][32 * 64];     // per-wave [q][kc], xor-swizzled

    const u16* kbase = K + ((long long)(b * S_LEN)) * DM + h * DHEAD;
    const u16* vbase = VT + ((long long)((b * NHEAD + h) * DHEAD)) * S_LEN;

    // two-stage pipeline: regs hold next tile, LDS holds committed tile
    bf16x8 kpre[2], vpre[2];
    int c0 = tid, c1 = tid + 256;
    int row0 = c0 >> 3, lc0 = (c0 & 7) ^ (row0 & 7);
    int row1 = c1 >> 3, lc1 = (c1 & 7) ^ (row1 & 7);

    // preload k-tile 0
    kpre[0] = *(const bf16x8*)(kbase + (long long)row0 * DM + lc0 * 8);
    vpre[0] = *(const bf16x8*)(vbase + (long long)row0 * S_LEN + lc0 * 8);
    kpre[1] = *(const bf16x8*)(kbase + (long long)row1 * DM + lc1 * 8);
    vpre[1] = *(const bf16x8*)(vbase + (long long)row1 * S_LEN + lc1 * 8);

    int it = 0;   // running tile counter -> LDS buffer parity (continuous across reps)
#pragma unroll 1
    for (int rep = 0; rep < 2; ++rep) {
        int qt = rep ? 15 - pi : pi;            // 128-row q-tile index
        // Q fragments for both 16-row sub-tiles
        bf16x8 aq[2][2];
#pragma unroll
        for (int sub = 0; sub < 2; ++sub) {
            int qrow = qt * 128 + w * 32 + sub * 16 + l16;
            const u16* qp = Q + ((long long)(b * S_LEN + qrow)) * DM + h * DHEAD + quad * 8;
            aq[sub][0] = *(const bf16x8*)(qp);
            aq[sub][1] = *(const bf16x8*)(qp + 32);
        }

        f32x4 o[2][4] = {};
        float m_r[2] = {-__builtin_inff(), -__builtin_inff()};
        float l_r[2] = {0.f, 0.f};

        int kts = 2 * qt + 2;
#pragma unroll 1
        for (int kt = 0; kt < kts; ++kt) {
            u16* Kb_ = Kl[it & 1];
            u16* Vb_ = Vl[it & 1];
            // commit prefetched tile to this iteration's buffer
            *(bf16x8*)((char*)Kb_ + c0 * 16) = kpre[0];
            *(bf16x8*)((char*)Vb_ + c0 * 16) = vpre[0];
            *(bf16x8*)((char*)Kb_ + c1 * 16) = kpre[1];
            *(bf16x8*)((char*)Vb_ + c1 * 16) = vpre[1];
            // issue global prefetch of the next tile (tile 0 of next rep at the seam)
            {
                int nk0 = (kt + 1 < kts ? kt + 1 : 0) * 64;
                kpre[0] = *(const bf16x8*)(kbase + (long long)(nk0 + row0) * DM + lc0 * 8);
                vpre[0] = *(const bf16x8*)(vbase + (long long)row0 * S_LEN + nk0 + lc0 * 8);
                kpre[1] = *(const bf16x8*)(kbase + (long long)(nk0 + row1) * DM + lc1 * 8);
                vpre[1] = *(const bf16x8*)(vbase + (long long)row1 * S_LEN + nk0 + lc1 * 8);
            }
            __syncthreads();     // tile visible; prev-buffer readers are past this fence

            // ---- K fragments (shared by both q-subtiles) ----
            bf16x8 ak0[4], ak1[4];
#pragma unroll
            for (int nt = 0; nt < 4; ++nt) {
                int row = nt * 16 + l16;
                ak0[nt] = *(const bf16x8*)(Kb_ + row * 64 + (quad ^ (row & 7)) * 8);
                ak1[nt] = *(const bf16x8*)(Kb_ + row * 64 + ((quad + 4) ^ (row & 7)) * 8);
            }

            bf16x8 bp[2][2];
            u16* pw = &Pl[w][0];
#pragma unroll
            for (int sub = 0; sub < 2; ++sub) {
                // ---- S^T = K Q^T : rows kc (regs), cols q = l16 ----
                f32x4 s[4];
#pragma unroll
                for (int nt = 0; nt < 4; ++nt) {
                    f32x4 a = {};
                    a = __builtin_amdgcn_mfma_f32_16x16x32_bf16(ak0[nt], aq[sub][0], a, 0, 0, 0);
                    a = __builtin_amdgcn_mfma_f32_16x16x32_bf16(ak1[nt], aq[sub][1], a, 0, 0, 0);
                    s[nt] = a;
                }
                // causal mask (only the last two k-tiles can touch the diagonal)
                if (kt >= 2 * qt) {
                    int qg = qt * 128 + w * 32 + sub * 16 + l16;
#pragma unroll
                    for (int nt = 0; nt < 4; ++nt) {
#pragma unroll
                        for (int r = 0; r < 4; ++r) {
                            int kg = kt * 64 + nt * 16 + quad * 4 + r;
                            if (kg > qg) s[nt][r] = -__builtin_inff();
                        }
                    }
                }
                // ---- per-lane online softmax in exp2 domain ----
                float mx = s[0][0];
#pragma unroll
                for (int nt = 0; nt < 4; ++nt)
#pragma unroll
                    for (int r = 0; r < 4; ++r) mx = fmaxf(mx, s[nt][r]);
                mx = fmaxf(mx, __shfl_xor(mx, 16, 64));
                mx = fmaxf(mx, __shfl_xor(mx, 32, 64));
                float mnew = fmaxf(m_r[sub], mx);
                float alpha = fexp2(m_r[sub] - mnew);
                m_r[sub] = mnew;
#pragma unroll
                for (int nt = 0; nt < 4; ++nt)
#pragma unroll
                    for (int r = 0; r < 4; ++r) s[nt][r] = fexp2(s[nt][r] - mnew);
                float sum = 0.f;
#pragma unroll
                for (int nt = 0; nt < 4; ++nt)
#pragma unroll
                    for (int r = 0; r < 4; ++r) sum += s[nt][r];
                sum += __shfl_xor(sum, 16, 64);
                sum += __shfl_xor(sum, 32, 64);
                l_r[sub] = l_r[sub] * alpha + sum;
#pragma unroll
                for (int dt = 0; dt < 4; ++dt)
#pragma unroll
                    for (int r = 0; r < 4; ++r) o[sub][dt][r] *= alpha;

                // ---- P[q][kc] pack, xor-swizzled, per-wave, no barrier ----
                int prow = sub * 16 + l16;
#pragma unroll
                for (int nt = 0; nt < 4; ++nt) {
                    ushort4 pk;
                    pk.x = f2bf(s[nt][0]); pk.y = f2bf(s[nt][1]);
                    pk.z = f2bf(s[nt][2]); pk.w = f2bf(s[nt][3]);
                    int chunk = (nt * 2 + (quad >> 1)) ^ (l16 & 7);
                    *(ushort4*)(pw + prow * 64 + chunk * 8 + (quad & 1) * 4) = pk;
                }
                bp[sub][0] = *(const bf16x8*)(pw + prow * 64 + (quad ^ (l16 & 7)) * 8);
                bp[sub][1] = *(const bf16x8*)(pw + prow * 64 + ((quad + 4) ^ (l16 & 7)) * 8);
            }

            // ---- V fragments (shared) + PV MFMAs ----
#pragma unroll
            for (int dt = 0; dt < 4; ++dt) {
                int row = dt * 16 + l16;
                bf16x8 av0 = *(const bf16x8*)(Vb_ + row * 64 + (quad ^ (row & 7)) * 8);
                bf16x8 av1 = *(const bf16x8*)(Vb_ + row * 64 + ((quad + 4) ^ (row & 7)) * 8);
#pragma unroll
                for (int sub = 0; sub < 2; ++sub) {
                    o[sub][dt] = __builtin_amdgcn_mfma_f32_16x16x32_bf16(av0, bp[sub][0],
                                                                         o[sub][dt], 0, 0, 0);
                    o[sub][dt] = __builtin_amdgcn_mfma_f32_16x16x32_bf16(av1, bp[sub][1],
                                                                         o[sub][dt], 0, 0, 0);
                }
            }
            ++it;
        }

        // ---- epilogue: o[sub][dt] holds O^T[d][q=l16]; l per-lane ----
#pragma unroll
        for (int sub = 0; sub < 2; ++sub) {
            float inv_l = 1.f / l_r[sub];
            u16* yp = Y + ((long long)(b * S_LEN + qt * 128 + w * 32 + sub * 16 + l16)) * DM
                      + h * DHEAD;
#pragma unroll
            for (int dt = 0; dt < 4; ++dt) {
                ushort4 yk;
                yk.x = f2bf(o[sub][dt][0] * inv_l);
                yk.y = f2bf(o[sub][dt][1] * inv_l);
                yk.z = f2bf(o[sub][dt][2] * inv_l);
                yk.w = f2bf(o[sub][dt][3] * inv_l);
                *(ushort4*)(yp + dt * 16 + quad * 4) = yk;
            }
        }
    }
}

extern "C" void kernel_launch(void* const* d_in, const int* in_sizes, int n_in,
                              void* d_out, int out_size, void* d_ws, size_t ws_size,
                              hipStream_t stream) {
    const float* x  = (const float*)d_in[0];
    const float* Wq = (const float*)d_in[1];
    const float* bq = (const float*)d_in[2];
    const float* Wk = (const float*)d_in[3];
    const float* bk = (const float*)d_in[4];
    const float* Wv = (const float*)d_in[5];
    const float* bv = (const float*)d_in[6];
    const float* Wo = (const float*)d_in[7];
    const float* bo = (const float*)d_in[8];

    const long long M = 2LL * S_LEN;          // 4096

    char* ws = (char*)d_ws;
    u16* xb   = (u16*)(ws);                        // 16 MB
    u16* Wqkv = (u16*)(ws + 16 * 1024 * 1024);     // 24 MB
    u16* Wob  = (u16*)(ws + 40 * 1024 * 1024);     // 8 MB
    u16* Qb   = (u16*)(ws + 48 * 1024 * 1024);     // 16 MB each
    u16* Kb   = (u16*)(ws + 64 * 1024 * 1024);
    u16* Vb   = (u16*)(ws + 80 * 1024 * 1024);     // raw V (bias added)
    u16* Yb   = (u16*)(ws + 96 * 1024 * 1024);
    u16* VTb  = (u16*)(ws + 112 * 1024 * 1024);    // sigmoid(V)^T [b,h,d,s]

    cast_all<<<24576, 256, 0, stream>>>(x, Wq, Wk, Wv, Wo, xb, Wqkv, Wob);

    dim3 gqkv(32, 48);
    gemm_qkv<<<gqkv, 256, 0, stream>>>(xb, Wqkv, bq, bk, bv, Qb, Kb, Vb, (int)M, DM);

    rope_vsig<<<34816, 256, 0, stream>>>(Qb, Kb, Vb, VTb);

    flash_attn<<<2 * NHEAD * 8, 256, 0, stream>>>(Qb, Kb, VTb, Yb);

    dim3 gg(32, 16);
    gemm_bt_f32<<<gg, 256, 0, stream>>>(Yb, Wob, bo, (float*)d_out, (int)M, DM, DM);
}